// Round 1
// baseline (891.826 us; speedup 1.0000x reference)
//
#include <hip/hip_runtime.h>
#include <math.h>

#define N_NODES 131072
#define N_EDGES 524288
#define IN_DIM_ 78
#define HID_ 64
#define HEADS_ 4
#define NG 4096
#define NPG 32
#define NLAYERS 3
#define NEG_SLOPE 0.2f

// ---------------- CSR build ----------------

__global__ void init_counts(int* __restrict__ cnt) {
    int n = blockIdx.x * blockDim.x + threadIdx.x;
    if (n < N_NODES) cnt[n] = 1;   // 1 = the self loop
}

__global__ void count_edges(const int* __restrict__ dst, int* __restrict__ cnt) {
    int e = blockIdx.x * blockDim.x + threadIdx.x;
    if (e < N_EDGES) atomicAdd(&cnt[dst[e]], 1);
}

// single-block exclusive scan of N_NODES counts -> offsets[N_NODES+1]
__global__ void scan_kernel(const int* __restrict__ cnt, int* __restrict__ offsets) {
    __shared__ int sums[1024];
    const int t = threadIdx.x;
    const int CHUNK = N_NODES / 1024;  // 128
    int base = t * CHUNK;
    int s = 0;
    for (int j = 0; j < CHUNK; ++j) s += cnt[base + j];
    sums[t] = s;
    __syncthreads();
    for (int off = 1; off < 1024; off <<= 1) {
        int v = (t >= off) ? sums[t - off] : 0;
        __syncthreads();
        sums[t] += v;
        __syncthreads();
    }
    int run = (t == 0) ? 0 : sums[t - 1];
    for (int j = 0; j < CHUNK; ++j) {
        int c = cnt[base + j];
        offsets[base + j] = run;
        run += c;
    }
    if (t == 1023) offsets[N_NODES] = run;   // = N_EDGES + N_NODES
}

__global__ void place_self(const int* __restrict__ offsets, int* __restrict__ cursor,
                           int* __restrict__ csr_src) {
    int n = blockIdx.x * blockDim.x + threadIdx.x;
    if (n < N_NODES) {
        int o = offsets[n];
        csr_src[o] = n;          // self loop first
        cursor[n] = o + 1;
    }
}

__global__ void scatter_edges(const int* __restrict__ src, const int* __restrict__ dst,
                              int* __restrict__ cursor, int* __restrict__ csr_src) {
    int e = blockIdx.x * blockDim.x + threadIdx.x;
    if (e < N_EDGES) {
        int d = dst[e];
        int pos = atomicAdd(&cursor[d], 1);
        csr_src[pos] = src[e];
    }
}

// ---------------- GEMM (h = A @ W) + fused alpha_src / alpha_dst ----------------
// Block: 256 threads computes 64 rows x 64 cols (one head). Grid: (N/64, HEADS).
template<int K>
__global__ __launch_bounds__(256)
void gemm_alpha(const float* __restrict__ A, const float* __restrict__ W,
                const float* __restrict__ a_src, const float* __restrict__ a_dst,
                float* __restrict__ h, float* __restrict__ als, float* __restrict__ ald) {
    constexpr int LDA = K + 2;             // pad: stride not a multiple of 32
    __shared__ float As[64 * LDA];
    __shared__ float Bs[K * 64];
    const int tid = threadIdx.x;
    const int rowBase = blockIdx.x * 64;
    const int head = blockIdx.y;

    for (int i = tid; i < 64 * K; i += 256) {
        int r = i / K, k = i - r * K;
        As[r * LDA + k] = A[(size_t)(rowBase + r) * K + k];
    }
    for (int i = tid; i < K * 64; i += 256) {
        int k = i >> 6, c = i & 63;
        Bs[k * 64 + c] = W[k * 256 + head * 64 + c];
    }
    __syncthreads();

    const int tx = tid & 15, ty = tid >> 4;
    const int r0 = ty * 4, c0 = tx * 4;
    float acc[4][4] = {};
    #pragma unroll 2
    for (int k = 0; k < K; ++k) {
        float4 bv = *(const float4*)&Bs[k * 64 + c0];
        #pragma unroll
        for (int i = 0; i < 4; ++i) {
            float a = As[(r0 + i) * LDA + k];
            acc[i][0] += a * bv.x;
            acc[i][1] += a * bv.y;
            acc[i][2] += a * bv.z;
            acc[i][3] += a * bv.w;
        }
    }

    float4 asv = *(const float4*)&a_src[head * 64 + c0];
    float4 adv = *(const float4*)&a_dst[head * 64 + c0];
    #pragma unroll
    for (int i = 0; i < 4; ++i) {
        int row = rowBase + r0 + i;
        float4 v = make_float4(acc[i][0], acc[i][1], acc[i][2], acc[i][3]);
        *(float4*)&h[(size_t)row * 256 + head * 64 + c0] = v;
        float ps = v.x * asv.x + v.y * asv.y + v.z * asv.z + v.w * asv.w;
        float pd = v.x * adv.x + v.y * adv.y + v.z * adv.z + v.w * adv.w;
        #pragma unroll
        for (int m = 1; m < 16; m <<= 1) {
            ps += __shfl_xor(ps, m, 64);
            pd += __shfl_xor(pd, m, 64);
        }
        if (tx == 0) {
            als[row * 4 + head] = ps;
            ald[row * 4 + head] = pd;
        }
    }
}

// ---------------- per-node softmax-weighted aggregation ----------------
// one wave per node; lane = d (0..63); 4 heads in registers
__global__ __launch_bounds__(256)
void aggregate(const int* __restrict__ offsets, const int* __restrict__ csr_src,
               const float* __restrict__ h, const float* __restrict__ als,
               const float* __restrict__ ald, const float* __restrict__ bias,
               float* __restrict__ hout) {
    const int wid = threadIdx.x >> 6;
    const int lane = threadIdx.x & 63;
    const int n = blockIdx.x * 4 + wid;

    float4 adv = *(const float4*)&ald[n * 4];
    const int o0 = offsets[n], o1 = offsets[n + 1];

    float acc0 = 0.f, acc1 = 0.f, acc2 = 0.f, acc3 = 0.f;
    float den0 = 0.f, den1 = 0.f, den2 = 0.f, den3 = 0.f;

    for (int i = o0; i < o1; ++i) {
        int s = csr_src[i];
        float4 asv = *(const float4*)&als[s * 4];
        float e0 = asv.x + adv.x; e0 = e0 > 0.f ? e0 : NEG_SLOPE * e0;
        float e1 = asv.y + adv.y; e1 = e1 > 0.f ? e1 : NEG_SLOPE * e1;
        float e2 = asv.z + adv.z; e2 = e2 > 0.f ? e2 : NEG_SLOPE * e2;
        float e3 = asv.w + adv.w; e3 = e3 > 0.f ? e3 : NEG_SLOPE * e3;
        float p0 = __expf(e0), p1 = __expf(e1), p2 = __expf(e2), p3 = __expf(e3);
        const float* hp = &h[(size_t)s * 256 + lane];
        float h0 = hp[0], h1 = hp[64], h2 = hp[128], h3 = hp[192];
        den0 += p0; den1 += p1; den2 += p2; den3 += p3;
        acc0 += p0 * h0; acc1 += p1 * h1; acc2 += p2 * h2; acc3 += p3 * h3;
    }

    float v = 0.25f * (acc0 / den0 + acc1 / den1 + acc2 / den2 + acc3 / den3) + bias[lane];
    hout[(size_t)n * 64 + lane] = v > 0.f ? v : 0.f;
}

// ---------------- per-graph pooling (32 consecutive nodes) ----------------
__global__ __launch_bounds__(256)
void pool_kernel(const float* __restrict__ hout, float* __restrict__ pooled, int layer) {
    const int wid = threadIdx.x >> 6, lane = threadIdx.x & 63;
    const int g = blockIdx.x * 4 + wid;
    float s = 0.f;
    const float* p = &hout[(size_t)g * NPG * 64 + lane];
    #pragma unroll 8
    for (int i = 0; i < NPG; ++i) s += p[i * 64];
    pooled[(g * NLAYERS + layer) * 64 + lane] = s;
}

// ---------------- final layer-attention ----------------
__global__ __launch_bounds__(256)
void final_kernel(const float* __restrict__ pooled, const float* __restrict__ pw,
                  const float* __restrict__ pb, float* __restrict__ out) {
    const int wid = threadIdx.x >> 6, lane = threadIdx.x & 63;
    const int g = blockIdx.x * 4 + wid;
    float v0 = pooled[(g * 3 + 0) * 64 + lane];
    float v1 = pooled[(g * 3 + 1) * 64 + lane];
    float v2 = pooled[(g * 3 + 2) * 64 + lane];
    float w = pw[lane];
    float l0 = v0 * w, l1 = v1 * w, l2 = v2 * w;
    #pragma unroll
    for (int m = 1; m < 64; m <<= 1) {
        l0 += __shfl_xor(l0, m, 64);
        l1 += __shfl_xor(l1, m, 64);
        l2 += __shfl_xor(l2, m, 64);
    }
    float bb = pb[0];
    l0 += bb; l1 += bb; l2 += bb;
    float mx = fmaxf(l0, fmaxf(l1, l2));
    float e0 = __expf(l0 - mx), e1 = __expf(l1 - mx), e2 = __expf(l2 - mx);
    float inv = 1.f / (e0 + e1 + e2);
    out[(size_t)g * 64 + lane] = (v0 * e0 + v1 * e1 + v2 * e2) * inv;
}

// ---------------- launch ----------------
extern "C" void kernel_launch(void* const* d_in, const int* in_sizes, int n_in,
                              void* d_out, int out_size, void* d_ws, size_t ws_size,
                              hipStream_t stream) {
    const float* x  = (const float*)d_in[0];
    const int*   ei = (const int*)d_in[1];
    const float* W[3]    = {(const float*)d_in[3], (const float*)d_in[7],  (const float*)d_in[11]};
    const float* asrc[3] = {(const float*)d_in[4], (const float*)d_in[8],  (const float*)d_in[12]};
    const float* adst[3] = {(const float*)d_in[5], (const float*)d_in[9],  (const float*)d_in[13]};
    const float* bias[3] = {(const float*)d_in[6], (const float*)d_in[10], (const float*)d_in[14]};
    const float* pw = (const float*)d_in[15];
    const float* pb = (const float*)d_in[16];
    float* out = (float*)d_out;

    char* ws = (char*)d_ws;
    size_t off = 0;
    auto alloc = [&](size_t bytes) -> void* {
        void* p = ws + off;
        off = (off + bytes + 255) & ~(size_t)255;
        return p;
    };
    int*   offsets = (int*)alloc((N_NODES + 1) * 4);
    int*   cursor  = (int*)alloc(N_NODES * 4);                  // doubles as cnt
    int*   csr_src = (int*)alloc((size_t)(N_EDGES + N_NODES) * 4);
    float* h       = (float*)alloc((size_t)N_NODES * 256 * 4);  // 134 MB
    float* als     = (float*)alloc((size_t)N_NODES * 4 * 4);
    float* ald     = (float*)alloc((size_t)N_NODES * 4 * 4);
    float* hbuf0   = (float*)alloc((size_t)N_NODES * 64 * 4);
    float* hbuf1   = (float*)alloc((size_t)N_NODES * 64 * 4);
    float* pooled  = (float*)alloc((size_t)NG * 3 * 64 * 4);
    (void)ws_size; (void)in_sizes; (void)n_in; (void)out_size;

    const int* srcp = ei;
    const int* dstp = ei + N_EDGES;

    init_counts<<<N_NODES / 256, 256, 0, stream>>>(cursor);
    count_edges<<<N_EDGES / 256, 256, 0, stream>>>(dstp, cursor);
    scan_kernel<<<1, 1024, 0, stream>>>(cursor, offsets);
    place_self<<<N_NODES / 256, 256, 0, stream>>>(offsets, cursor, csr_src);
    scatter_edges<<<N_EDGES / 256, 256, 0, stream>>>(srcp, dstp, cursor, csr_src);

    const float* in = x;
    for (int l = 0; l < 3; ++l) {
        dim3 grid(N_NODES / 64, HEADS_);
        if (l == 0)
            gemm_alpha<IN_DIM_><<<grid, 256, 0, stream>>>(in, W[l], asrc[l], adst[l], h, als, ald);
        else
            gemm_alpha<HID_><<<grid, 256, 0, stream>>>(in, W[l], asrc[l], adst[l], h, als, ald);
        float* ho = (l & 1) ? hbuf1 : hbuf0;
        aggregate<<<N_NODES / 4, 256, 0, stream>>>(offsets, csr_src, h, als, ald, bias[l], ho);
        pool_kernel<<<NG / 4, 256, 0, stream>>>(ho, pooled, l);
        in = ho;
    }
    final_kernel<<<NG / 4, 256, 0, stream>>>(pooled, pw, pb, out);
}

// Round 2
// 812.082 us; speedup vs baseline: 1.0982x; 1.0982x over previous
//
#include <hip/hip_runtime.h>
#include <math.h>

#define N_NODES 131072
#define N_EDGES 524288
#define IN_DIM_ 78
#define HID_ 64
#define HEADS_ 4
#define NG 4096
#define NPG 32
#define NLAYERS 3
#define NEG_SLOPE 0.2f

// ---------------- CSR build ----------------

__global__ void init_counts(int* __restrict__ cnt) {
    int n = blockIdx.x * blockDim.x + threadIdx.x;
    if (n < N_NODES) cnt[n] = 1;   // 1 = the self loop
}

__global__ void count_edges(const int* __restrict__ dst, int* __restrict__ cnt) {
    int e = blockIdx.x * blockDim.x + threadIdx.x;
    if (e < N_EDGES) atomicAdd(&cnt[dst[e]], 1);
}

// single-block exclusive scan of N_NODES counts -> offsets[N_NODES+1]
__global__ void scan_kernel(const int* __restrict__ cnt, int* __restrict__ offsets) {
    __shared__ int sums[1024];
    const int t = threadIdx.x;
    const int CHUNK = N_NODES / 1024;  // 128
    int base = t * CHUNK;
    int s = 0;
    for (int j = 0; j < CHUNK / 4; ++j) {
        int4 v = ((const int4*)(cnt + base))[j];
        s += v.x + v.y + v.z + v.w;
    }
    sums[t] = s;
    __syncthreads();
    for (int off = 1; off < 1024; off <<= 1) {
        int v = (t >= off) ? sums[t - off] : 0;
        __syncthreads();
        sums[t] += v;
        __syncthreads();
    }
    int run = (t == 0) ? 0 : sums[t - 1];
    for (int j = 0; j < CHUNK / 4; ++j) {
        int4 c = ((const int4*)(cnt + base))[j];
        int4 o;
        o.x = run; run += c.x;
        o.y = run; run += c.y;
        o.z = run; run += c.z;
        o.w = run; run += c.w;
        ((int4*)(offsets + base))[j] = o;
    }
    if (t == 1023) offsets[N_NODES] = run;   // = N_EDGES + N_NODES
}

__global__ void place_self(const int* __restrict__ offsets, int* __restrict__ cursor,
                           int* __restrict__ csr_src) {
    int n = blockIdx.x * blockDim.x + threadIdx.x;
    if (n < N_NODES) {
        int o = offsets[n];
        csr_src[o] = n;          // self loop first
        cursor[n] = o + 1;
    }
}

__global__ void scatter_edges(const int* __restrict__ src, const int* __restrict__ dst,
                              int* __restrict__ cursor, int* __restrict__ csr_src) {
    int e = blockIdx.x * blockDim.x + threadIdx.x;
    if (e < N_EDGES) {
        int d = dst[e];
        int pos = atomicAdd(&cursor[d], 1);
        csr_src[pos] = src[e];
    }
}

// ---------------- GEMM (h = A @ W) + fused alpha_src / alpha_dst ----------------
// Block: 256 threads = 4 waves x 8 rows = 32 rows; all 256 output cols.
// Lane owns cols c = lane*4..lane*4+3 (head = lane>>4, dims (lane&15)*4..+3).
// W staged in LDS in two K-halves (<=40KB); A read via wave-uniform scalar loads.
template<int K>
__global__ __launch_bounds__(256)
void gemm_alpha(const float* __restrict__ A, const float* __restrict__ W,
                const float* __restrict__ a_src, const float* __restrict__ a_dst,
                float* __restrict__ h, float* __restrict__ als, float* __restrict__ ald) {
    constexpr int KH = (K + 1) / 2;          // 39 (K=78) or 32 (K=64)
    __shared__ float Bs[KH * 256];
    const int tid = threadIdx.x;
    const int lane = tid & 63;
    const int warp = __builtin_amdgcn_readfirstlane(tid >> 6);
    const int row0 = blockIdx.x * 32 + warp * 8;
    const float* __restrict__ Arow = A + (size_t)row0 * K;

    float4 acc[8];
    #pragma unroll
    for (int r = 0; r < 8; ++r) acc[r] = make_float4(0.f, 0.f, 0.f, 0.f);

    for (int half = 0; half < 2; ++half) {
        const int kbeg = half * KH;
        const int kcnt = (half == 0) ? KH : (K - KH);
        // stage W[kbeg..kbeg+kcnt) rows (contiguous region) as float4
        const float4* __restrict__ Wsrc = (const float4*)(W + (size_t)kbeg * 256);
        const int nf4 = kcnt * 64;
        for (int i = tid; i < nf4; i += 256) ((float4*)Bs)[i] = Wsrc[i];
        __syncthreads();

        #pragma unroll 4
        for (int kk = 0; kk < kcnt; ++kk) {
            const int k = kbeg + kk;
            float4 bv = *(const float4*)&Bs[kk * 256 + lane * 4];
            #pragma unroll
            for (int r = 0; r < 8; ++r) {
                float a = Arow[(size_t)r * K + k];
                acc[r].x += a * bv.x;
                acc[r].y += a * bv.y;
                acc[r].z += a * bv.z;
                acc[r].w += a * bv.w;
            }
        }
        __syncthreads();
    }

    // epilogue: write h + fused alpha dot products
    const int head = lane >> 4;
    const int d4 = (lane & 15) * 4;
    float4 asv = *(const float4*)&a_src[head * 64 + d4];
    float4 adv = *(const float4*)&a_dst[head * 64 + d4];
    #pragma unroll
    for (int r = 0; r < 8; ++r) {
        const int row = row0 + r;
        *(float4*)&h[(size_t)row * 256 + lane * 4] = acc[r];
        float ps = acc[r].x * asv.x + acc[r].y * asv.y + acc[r].z * asv.z + acc[r].w * asv.w;
        float pd = acc[r].x * adv.x + acc[r].y * adv.y + acc[r].z * adv.z + acc[r].w * adv.w;
        #pragma unroll
        for (int m = 1; m < 16; m <<= 1) {
            ps += __shfl_xor(ps, m, 64);
            pd += __shfl_xor(pd, m, 64);
        }
        if ((lane & 15) == 0) {
            als[row * 4 + head] = ps;
            ald[row * 4 + head] = pd;
        }
    }
}

// ---------------- per-node softmax-weighted aggregation ----------------
// one wave per node; lane -> (head = lane>>4, dims d4..d4+3); 1 b128 h-load per edge.
__device__ __forceinline__ float pick4(float4 v, int idx) {
    float r = v.x;
    r = (idx == 1) ? v.y : r;
    r = (idx == 2) ? v.z : r;
    r = (idx == 3) ? v.w : r;
    return r;
}

__global__ __launch_bounds__(256)
void aggregate(const int* __restrict__ offsets, const int* __restrict__ csr_src,
               const float* __restrict__ h, const float* __restrict__ als,
               const float* __restrict__ ald, const float* __restrict__ bias,
               float* __restrict__ hout) {
    const int lane = threadIdx.x & 63;
    const int wid = __builtin_amdgcn_readfirstlane(threadIdx.x >> 6);
    const int n = blockIdx.x * 4 + wid;
    const int head = lane >> 4;
    const int d4 = (lane & 15) * 4;

    const int o0 = __builtin_amdgcn_readfirstlane(offsets[n]);
    const int o1 = __builtin_amdgcn_readfirstlane(offsets[n + 1]);

    const float ad_h = pick4(*(const float4*)&ald[n * 4], head);

    float4 acc = make_float4(0.f, 0.f, 0.f, 0.f);
    float den = 0.f;

    int i = o0;
    for (; i + 4 <= o1; i += 4) {
        int s0 = __builtin_amdgcn_readfirstlane(csr_src[i + 0]);
        int s1 = __builtin_amdgcn_readfirstlane(csr_src[i + 1]);
        int s2 = __builtin_amdgcn_readfirstlane(csr_src[i + 2]);
        int s3 = __builtin_amdgcn_readfirstlane(csr_src[i + 3]);
        float4 as0 = *(const float4*)&als[s0 * 4];
        float4 as1 = *(const float4*)&als[s1 * 4];
        float4 as2 = *(const float4*)&als[s2 * 4];
        float4 as3 = *(const float4*)&als[s3 * 4];
        float4 h0 = *(const float4*)&h[(size_t)s0 * 256 + lane * 4];
        float4 h1 = *(const float4*)&h[(size_t)s1 * 256 + lane * 4];
        float4 h2 = *(const float4*)&h[(size_t)s2 * 256 + lane * 4];
        float4 h3 = *(const float4*)&h[(size_t)s3 * 256 + lane * 4];
        float e0 = pick4(as0, head) + ad_h; e0 = e0 > 0.f ? e0 : NEG_SLOPE * e0;
        float e1 = pick4(as1, head) + ad_h; e1 = e1 > 0.f ? e1 : NEG_SLOPE * e1;
        float e2 = pick4(as2, head) + ad_h; e2 = e2 > 0.f ? e2 : NEG_SLOPE * e2;
        float e3 = pick4(as3, head) + ad_h; e3 = e3 > 0.f ? e3 : NEG_SLOPE * e3;
        float p0 = __expf(e0), p1 = __expf(e1), p2 = __expf(e2), p3 = __expf(e3);
        den += p0 + p1 + p2 + p3;
        acc.x += p0 * h0.x + p1 * h1.x + p2 * h2.x + p3 * h3.x;
        acc.y += p0 * h0.y + p1 * h1.y + p2 * h2.y + p3 * h3.y;
        acc.z += p0 * h0.z + p1 * h1.z + p2 * h2.z + p3 * h3.z;
        acc.w += p0 * h0.w + p1 * h1.w + p2 * h2.w + p3 * h3.w;
    }
    for (; i < o1; ++i) {
        int s = __builtin_amdgcn_readfirstlane(csr_src[i]);
        float4 asv = *(const float4*)&als[s * 4];
        float4 hv = *(const float4*)&h[(size_t)s * 256 + lane * 4];
        float e = pick4(asv, head) + ad_h;
        e = e > 0.f ? e : NEG_SLOPE * e;
        float p = __expf(e);
        den += p;
        acc.x += p * hv.x; acc.y += p * hv.y; acc.z += p * hv.z; acc.w += p * hv.w;
    }

    const float rden = 1.f / den;
    float c0 = acc.x * rden, c1 = acc.y * rden, c2 = acc.z * rden, c3 = acc.w * rden;
    // sum across the 4 head-groups (lanes differing in bits 4,5)
    c0 += __shfl_xor(c0, 16, 64); c0 += __shfl_xor(c0, 32, 64);
    c1 += __shfl_xor(c1, 16, 64); c1 += __shfl_xor(c1, 32, 64);
    c2 += __shfl_xor(c2, 16, 64); c2 += __shfl_xor(c2, 32, 64);
    c3 += __shfl_xor(c3, 16, 64); c3 += __shfl_xor(c3, 32, 64);

    if (lane < 16) {
        float4 bv = *(const float4*)&bias[d4];
        float v0 = 0.25f * c0 + bv.x;
        float v1 = 0.25f * c1 + bv.y;
        float v2 = 0.25f * c2 + bv.z;
        float v3 = 0.25f * c3 + bv.w;
        float4 o;
        o.x = v0 > 0.f ? v0 : 0.f;
        o.y = v1 > 0.f ? v1 : 0.f;
        o.z = v2 > 0.f ? v2 : 0.f;
        o.w = v3 > 0.f ? v3 : 0.f;
        *(float4*)&hout[(size_t)n * 64 + d4] = o;
    }
}

// ---------------- per-graph pooling (32 consecutive nodes) ----------------
__global__ __launch_bounds__(256)
void pool_kernel(const float* __restrict__ hout, float* __restrict__ pooled, int layer) {
    const int wid = threadIdx.x >> 6, lane = threadIdx.x & 63;
    const int g = blockIdx.x * 4 + wid;
    float s = 0.f;
    const float* p = &hout[(size_t)g * NPG * 64 + lane];
    #pragma unroll 8
    for (int i = 0; i < NPG; ++i) s += p[i * 64];
    pooled[(g * NLAYERS + layer) * 64 + lane] = s;
}

// ---------------- final layer-attention ----------------
__global__ __launch_bounds__(256)
void final_kernel(const float* __restrict__ pooled, const float* __restrict__ pw,
                  const float* __restrict__ pb, float* __restrict__ out) {
    const int wid = threadIdx.x >> 6, lane = threadIdx.x & 63;
    const int g = blockIdx.x * 4 + wid;
    float v0 = pooled[(g * 3 + 0) * 64 + lane];
    float v1 = pooled[(g * 3 + 1) * 64 + lane];
    float v2 = pooled[(g * 3 + 2) * 64 + lane];
    float w = pw[lane];
    float l0 = v0 * w, l1 = v1 * w, l2 = v2 * w;
    #pragma unroll
    for (int m = 1; m < 64; m <<= 1) {
        l0 += __shfl_xor(l0, m, 64);
        l1 += __shfl_xor(l1, m, 64);
        l2 += __shfl_xor(l2, m, 64);
    }
    float bb = pb[0];
    l0 += bb; l1 += bb; l2 += bb;
    float mx = fmaxf(l0, fmaxf(l1, l2));
    float e0 = __expf(l0 - mx), e1 = __expf(l1 - mx), e2 = __expf(l2 - mx);
    float inv = 1.f / (e0 + e1 + e2);
    out[(size_t)g * 64 + lane] = (v0 * e0 + v1 * e1 + v2 * e2) * inv;
}

// ---------------- launch ----------------
extern "C" void kernel_launch(void* const* d_in, const int* in_sizes, int n_in,
                              void* d_out, int out_size, void* d_ws, size_t ws_size,
                              hipStream_t stream) {
    const float* x  = (const float*)d_in[0];
    const int*   ei = (const int*)d_in[1];
    const float* W[3]    = {(const float*)d_in[3], (const float*)d_in[7],  (const float*)d_in[11]};
    const float* asrc[3] = {(const float*)d_in[4], (const float*)d_in[8],  (const float*)d_in[12]};
    const float* adst[3] = {(const float*)d_in[5], (const float*)d_in[9],  (const float*)d_in[13]};
    const float* bias[3] = {(const float*)d_in[6], (const float*)d_in[10], (const float*)d_in[14]};
    const float* pw = (const float*)d_in[15];
    const float* pb = (const float*)d_in[16];
    float* out = (float*)d_out;

    char* ws = (char*)d_ws;
    size_t off = 0;
    auto alloc = [&](size_t bytes) -> void* {
        void* p = ws + off;
        off = (off + bytes + 255) & ~(size_t)255;
        return p;
    };
    int*   offsets = (int*)alloc((N_NODES + 1) * 4);
    int*   cursor  = (int*)alloc(N_NODES * 4);                  // doubles as cnt
    int*   csr_src = (int*)alloc((size_t)(N_EDGES + N_NODES) * 4);
    float* h       = (float*)alloc((size_t)N_NODES * 256 * 4);  // 134 MB
    float* als     = (float*)alloc((size_t)N_NODES * 4 * 4);
    float* ald     = (float*)alloc((size_t)N_NODES * 4 * 4);
    float* hbuf0   = (float*)alloc((size_t)N_NODES * 64 * 4);
    float* hbuf1   = (float*)alloc((size_t)N_NODES * 64 * 4);
    float* pooled  = (float*)alloc((size_t)NG * 3 * 64 * 4);
    (void)ws_size; (void)in_sizes; (void)n_in; (void)out_size;

    const int* srcp = ei;
    const int* dstp = ei + N_EDGES;

    init_counts<<<N_NODES / 256, 256, 0, stream>>>(cursor);
    count_edges<<<N_EDGES / 256, 256, 0, stream>>>(dstp, cursor);
    scan_kernel<<<1, 1024, 0, stream>>>(cursor, offsets);
    place_self<<<N_NODES / 256, 256, 0, stream>>>(offsets, cursor, csr_src);
    scatter_edges<<<N_EDGES / 256, 256, 0, stream>>>(srcp, dstp, cursor, csr_src);

    const float* in = x;
    for (int l = 0; l < 3; ++l) {
        if (l == 0)
            gemm_alpha<IN_DIM_><<<N_NODES / 32, 256, 0, stream>>>(in, W[l], asrc[l], adst[l], h, als, ald);
        else
            gemm_alpha<HID_><<<N_NODES / 32, 256, 0, stream>>>(in, W[l], asrc[l], adst[l], h, als, ald);
        float* ho = (l & 1) ? hbuf1 : hbuf0;
        aggregate<<<N_NODES / 4, 256, 0, stream>>>(offsets, csr_src, h, als, ald, bias[l], ho);
        pool_kernel<<<NG / 4, 256, 0, stream>>>(ho, pooled, l);
        in = ho;
    }
    final_kernel<<<NG / 4, 256, 0, stream>>>(pooled, pw, pb, out);
}

// Round 4
// 772.319 us; speedup vs baseline: 1.1547x; 1.0515x over previous
//
#include <hip/hip_runtime.h>
#include <math.h>

#define N_NODES 131072
#define N_EDGES 524288
#define IN_DIM_ 78
#define HID_ 64
#define HEADS_ 4
#define NG 4096
#define NPG 32
#define NLAYERS 3
#define NEG_SLOPE 0.2f

// ---------------- CSR build ----------------

__global__ void init_counts(int* __restrict__ cnt) {
    int n = blockIdx.x * blockDim.x + threadIdx.x;
    if (n < N_NODES) cnt[n] = 1;   // 1 = the self loop
}

__global__ void count_edges(const int* __restrict__ dst, int* __restrict__ cnt) {
    int e = blockIdx.x * blockDim.x + threadIdx.x;
    if (e < N_EDGES) atomicAdd(&cnt[dst[e]], 1);
}

// single-block exclusive scan of N_NODES counts -> offsets[N_NODES+1]
__global__ void scan_kernel(const int* __restrict__ cnt, int* __restrict__ offsets) {
    __shared__ int sums[1024];
    const int t = threadIdx.x;
    const int CHUNK = N_NODES / 1024;  // 128
    int base = t * CHUNK;
    int s = 0;
    for (int j = 0; j < CHUNK / 4; ++j) {
        int4 v = ((const int4*)(cnt + base))[j];
        s += v.x + v.y + v.z + v.w;
    }
    sums[t] = s;
    __syncthreads();
    for (int off = 1; off < 1024; off <<= 1) {
        int v = (t >= off) ? sums[t - off] : 0;
        __syncthreads();
        sums[t] += v;
        __syncthreads();
    }
    int run = (t == 0) ? 0 : sums[t - 1];
    for (int j = 0; j < CHUNK / 4; ++j) {
        int4 c = ((const int4*)(cnt + base))[j];
        int4 o;
        o.x = run; run += c.x;
        o.y = run; run += c.y;
        o.z = run; run += c.z;
        o.w = run; run += c.w;
        ((int4*)(offsets + base))[j] = o;
    }
    if (t == 1023) offsets[N_NODES] = run;   // = N_EDGES + N_NODES
}

__global__ void place_self(const int* __restrict__ offsets, int* __restrict__ cursor,
                           int* __restrict__ csr_src) {
    int n = blockIdx.x * blockDim.x + threadIdx.x;
    if (n < N_NODES) {
        int o = offsets[n];
        csr_src[o] = n;          // self loop first
        cursor[n] = o + 1;
    }
}

__global__ void scatter_edges(const int* __restrict__ src, const int* __restrict__ dst,
                              int* __restrict__ cursor, int* __restrict__ csr_src) {
    int e = blockIdx.x * blockDim.x + threadIdx.x;
    if (e < N_EDGES) {
        int d = dst[e];
        int pos = atomicAdd(&cursor[d], 1);
        csr_src[pos] = src[e];
    }
}

// ---------------- GEMM (h = A @ W) + fused alpha_src / alpha_dst ----------------
// Block: 256 threads = 8 row-groups (ty) x 32 col-threads (tx).
// Tile: 64 rows x 256 cols. Thread: 8 rows x 8 cols (cols tx*4 and 128+tx*4).
// A staged fully in LDS (zero-padded to KPAD); B staged in KB-row chunks.
// A reads are 2-address LDS broadcasts (free); B reads are contiguous b128.
template<int K, int KPAD, int KB>
__global__ __launch_bounds__(256)
void gemm_alpha(const float* __restrict__ A, const float* __restrict__ W,
                const float* __restrict__ a_src, const float* __restrict__ a_dst,
                float* __restrict__ h, float* __restrict__ als, float* __restrict__ ald) {
    __shared__ float As[64 * KPAD];
    __shared__ float Bs[KB * 256];
    const int tid = threadIdx.x;
    const int tx = tid & 31;
    const int ty = tid >> 5;
    const int row0 = blockIdx.x * 64;

    // stage A once (zero-pad k >= K)
    for (int i = tid; i < 64 * KPAD; i += 256) {
        int r = i / KPAD, k = i - r * KPAD;
        As[i] = (k < K) ? A[(size_t)(row0 + r) * K + k] : 0.f;
    }

    float4 acc0[8], acc1[8];
    #pragma unroll
    for (int r = 0; r < 8; ++r) {
        acc0[r] = make_float4(0.f, 0.f, 0.f, 0.f);
        acc1[r] = make_float4(0.f, 0.f, 0.f, 0.f);
    }

    for (int kbeg = 0; kbeg < KPAD; kbeg += KB) {
        // stage B rows [kbeg, kbeg+KB) as float4 (zero-pad k >= K)
        for (int i = tid; i < KB * 64; i += 256) {
            int k = kbeg + (i >> 6);
            float4 v = make_float4(0.f, 0.f, 0.f, 0.f);
            if (k < K) v = ((const float4*)(W + (size_t)k * 256))[i & 63];
            ((float4*)Bs)[i] = v;
        }
        __syncthreads();

        #pragma unroll 4
        for (int kk = 0; kk < KB; ++kk) {
            float4 b0 = *(const float4*)&Bs[kk * 256 + tx * 4];
            float4 b1 = *(const float4*)&Bs[kk * 256 + 128 + tx * 4];
            const float* ap = &As[(ty * 8) * KPAD + kbeg + kk];
            #pragma unroll
            for (int r = 0; r < 8; ++r) {
                float a = ap[(size_t)r * KPAD];
                acc0[r].x += a * b0.x; acc0[r].y += a * b0.y;
                acc0[r].z += a * b0.z; acc0[r].w += a * b0.w;
                acc1[r].x += a * b1.x; acc1[r].y += a * b1.y;
                acc1[r].z += a * b1.z; acc1[r].w += a * b1.w;
            }
        }
        __syncthreads();
    }

    // epilogue: write h + fused alpha dot products.
    // group0 cols tx*4..+3   -> head h0 = tx>>4 (0/1), dims (tx&15)*4..+3
    // group1 cols 128+tx*4   -> head h0+2 (2/3), same dims
    const int h0 = tx >> 4;
    const int d4 = (tx & 15) * 4;
    float4 as0 = *(const float4*)&a_src[h0 * 64 + d4];
    float4 ad0 = *(const float4*)&a_dst[h0 * 64 + d4];
    float4 as1 = *(const float4*)&a_src[(h0 + 2) * 64 + d4];
    float4 ad1 = *(const float4*)&a_dst[(h0 + 2) * 64 + d4];
    #pragma unroll
    for (int r = 0; r < 8; ++r) {
        const int row = row0 + ty * 8 + r;
        *(float4*)&h[(size_t)row * 256 + tx * 4]       = acc0[r];
        *(float4*)&h[(size_t)row * 256 + 128 + tx * 4] = acc1[r];
        float ps0 = acc0[r].x * as0.x + acc0[r].y * as0.y + acc0[r].z * as0.z + acc0[r].w * as0.w;
        float pd0 = acc0[r].x * ad0.x + acc0[r].y * ad0.y + acc0[r].z * ad0.z + acc0[r].w * ad0.w;
        float ps1 = acc1[r].x * as1.x + acc1[r].y * as1.y + acc1[r].z * as1.z + acc1[r].w * as1.w;
        float pd1 = acc1[r].x * ad1.x + acc1[r].y * ad1.y + acc1[r].z * ad1.z + acc1[r].w * ad1.w;
        #pragma unroll
        for (int m = 1; m < 16; m <<= 1) {
            ps0 += __shfl_xor(ps0, m, 64);
            pd0 += __shfl_xor(pd0, m, 64);
            ps1 += __shfl_xor(ps1, m, 64);
            pd1 += __shfl_xor(pd1, m, 64);
        }
        if ((tx & 15) == 0) {
            als[row * 4 + h0]     = ps0;
            ald[row * 4 + h0]     = pd0;
            als[row * 4 + h0 + 2] = ps1;
            ald[row * 4 + h0 + 2] = pd1;
        }
    }
}

// ---------------- per-node softmax-weighted aggregation ----------------
// one wave per node; lane -> (head = lane>>4, dims d4..d4+3); 1 b128 h-load per edge.
__device__ __forceinline__ float pick4(float4 v, int idx) {
    float r = v.x;
    r = (idx == 1) ? v.y : r;
    r = (idx == 2) ? v.z : r;
    r = (idx == 3) ? v.w : r;
    return r;
}

__global__ __launch_bounds__(256)
void aggregate(const int* __restrict__ offsets, const int* __restrict__ csr_src,
               const float* __restrict__ h, const float* __restrict__ als,
               const float* __restrict__ ald, const float* __restrict__ bias,
               float* __restrict__ hout) {
    const int lane = threadIdx.x & 63;
    const int wid = __builtin_amdgcn_readfirstlane(threadIdx.x >> 6);
    const int n = blockIdx.x * 4 + wid;
    const int head = lane >> 4;
    const int d4 = (lane & 15) * 4;

    const int o0 = __builtin_amdgcn_readfirstlane(offsets[n]);
    const int o1 = __builtin_amdgcn_readfirstlane(offsets[n + 1]);

    const float ad_h = pick4(*(const float4*)&ald[n * 4], head);

    float4 acc = make_float4(0.f, 0.f, 0.f, 0.f);
    float den = 0.f;

    int i = o0;
    for (; i + 4 <= o1; i += 4) {
        int s0 = __builtin_amdgcn_readfirstlane(csr_src[i + 0]);
        int s1 = __builtin_amdgcn_readfirstlane(csr_src[i + 1]);
        int s2 = __builtin_amdgcn_readfirstlane(csr_src[i + 2]);
        int s3 = __builtin_amdgcn_readfirstlane(csr_src[i + 3]);
        float4 as0 = *(const float4*)&als[s0 * 4];
        float4 as1 = *(const float4*)&als[s1 * 4];
        float4 as2 = *(const float4*)&als[s2 * 4];
        float4 as3 = *(const float4*)&als[s3 * 4];
        float4 h0 = *(const float4*)&h[(size_t)s0 * 256 + lane * 4];
        float4 h1 = *(const float4*)&h[(size_t)s1 * 256 + lane * 4];
        float4 h2 = *(const float4*)&h[(size_t)s2 * 256 + lane * 4];
        float4 h3 = *(const float4*)&h[(size_t)s3 * 256 + lane * 4];
        float e0 = pick4(as0, head) + ad_h; e0 = e0 > 0.f ? e0 : NEG_SLOPE * e0;
        float e1 = pick4(as1, head) + ad_h; e1 = e1 > 0.f ? e1 : NEG_SLOPE * e1;
        float e2 = pick4(as2, head) + ad_h; e2 = e2 > 0.f ? e2 : NEG_SLOPE * e2;
        float e3 = pick4(as3, head) + ad_h; e3 = e3 > 0.f ? e3 : NEG_SLOPE * e3;
        float p0 = __expf(e0), p1 = __expf(e1), p2 = __expf(e2), p3 = __expf(e3);
        den += p0 + p1 + p2 + p3;
        acc.x += p0 * h0.x + p1 * h1.x + p2 * h2.x + p3 * h3.x;
        acc.y += p0 * h0.y + p1 * h1.y + p2 * h2.y + p3 * h3.y;
        acc.z += p0 * h0.z + p1 * h1.z + p2 * h2.z + p3 * h3.z;
        acc.w += p0 * h0.w + p1 * h1.w + p2 * h2.w + p3 * h3.w;
    }
    for (; i < o1; ++i) {
        int s = __builtin_amdgcn_readfirstlane(csr_src[i]);
        float4 asv = *(const float4*)&als[s * 4];
        float4 hv = *(const float4*)&h[(size_t)s * 256 + lane * 4];
        float e = pick4(asv, head) + ad_h;
        e = e > 0.f ? e : NEG_SLOPE * e;
        float p = __expf(e);
        den += p;
        acc.x += p * hv.x; acc.y += p * hv.y; acc.z += p * hv.z; acc.w += p * hv.w;
    }

    const float rden = 1.f / den;
    float c0 = acc.x * rden, c1 = acc.y * rden, c2 = acc.z * rden, c3 = acc.w * rden;
    // sum across the 4 head-groups (lanes differing in bits 4,5)
    c0 += __shfl_xor(c0, 16, 64); c0 += __shfl_xor(c0, 32, 64);
    c1 += __shfl_xor(c1, 16, 64); c1 += __shfl_xor(c1, 32, 64);
    c2 += __shfl_xor(c2, 16, 64); c2 += __shfl_xor(c2, 32, 64);
    c3 += __shfl_xor(c3, 16, 64); c3 += __shfl_xor(c3, 32, 64);

    if (lane < 16) {
        float4 bv = *(const float4*)&bias[d4];
        float v0 = 0.25f * c0 + bv.x;
        float v1 = 0.25f * c1 + bv.y;
        float v2 = 0.25f * c2 + bv.z;
        float v3 = 0.25f * c3 + bv.w;
        float4 o;
        o.x = v0 > 0.f ? v0 : 0.f;
        o.y = v1 > 0.f ? v1 : 0.f;
        o.z = v2 > 0.f ? v2 : 0.f;
        o.w = v3 > 0.f ? v3 : 0.f;
        *(float4*)&hout[(size_t)n * 64 + d4] = o;
    }
}

// ---------------- per-graph pooling (32 consecutive nodes) ----------------
__global__ __launch_bounds__(256)
void pool_kernel(const float* __restrict__ hout, float* __restrict__ pooled, int layer) {
    const int wid = threadIdx.x >> 6, lane = threadIdx.x & 63;
    const int g = blockIdx.x * 4 + wid;
    float s = 0.f;
    const float* p = &hout[(size_t)g * NPG * 64 + lane];
    #pragma unroll 8
    for (int i = 0; i < NPG; ++i) s += p[i * 64];
    pooled[(g * NLAYERS + layer) * 64 + lane] = s;
}

// ---------------- final layer-attention ----------------
__global__ __launch_bounds__(256)
void final_kernel(const float* __restrict__ pooled, const float* __restrict__ pw,
                  const float* __restrict__ pb, float* __restrict__ out) {
    const int wid = threadIdx.x >> 6, lane = threadIdx.x & 63;
    const int g = blockIdx.x * 4 + wid;
    float v0 = pooled[(g * 3 + 0) * 64 + lane];
    float v1 = pooled[(g * 3 + 1) * 64 + lane];
    float v2 = pooled[(g * 3 + 2) * 64 + lane];
    float w = pw[lane];
    float l0 = v0 * w, l1 = v1 * w, l2 = v2 * w;
    #pragma unroll
    for (int m = 1; m < 64; m <<= 1) {
        l0 += __shfl_xor(l0, m, 64);
        l1 += __shfl_xor(l1, m, 64);
        l2 += __shfl_xor(l2, m, 64);
    }
    float bb = pb[0];
    l0 += bb; l1 += bb; l2 += bb;
    float mx = fmaxf(l0, fmaxf(l1, l2));
    float e0 = __expf(l0 - mx), e1 = __expf(l1 - mx), e2 = __expf(l2 - mx);
    float inv = 1.f / (e0 + e1 + e2);
    out[(size_t)g * 64 + lane] = (v0 * e0 + v1 * e1 + v2 * e2) * inv;
}

// ---------------- launch ----------------
extern "C" void kernel_launch(void* const* d_in, const int* in_sizes, int n_in,
                              void* d_out, int out_size, void* d_ws, size_t ws_size,
                              hipStream_t stream) {
    const float* x  = (const float*)d_in[0];
    const int*   ei = (const int*)d_in[1];
    const float* W[3]    = {(const float*)d_in[3], (const float*)d_in[7],  (const float*)d_in[11]};
    const float* asrc[3] = {(const float*)d_in[4], (const float*)d_in[8],  (const float*)d_in[12]};
    const float* adst[3] = {(const float*)d_in[5], (const float*)d_in[9],  (const float*)d_in[13]};
    const float* bias[3] = {(const float*)d_in[6], (const float*)d_in[10], (const float*)d_in[14]};
    const float* pw = (const float*)d_in[15];
    const float* pb = (const float*)d_in[16];
    float* out = (float*)d_out;

    char* ws = (char*)d_ws;
    size_t off = 0;
    auto alloc = [&](size_t bytes) -> void* {
        void* p = ws + off;
        off = (off + bytes + 255) & ~(size_t)255;
        return p;
    };
    int*   offsets = (int*)alloc((N_NODES + 1) * 4);
    int*   cursor  = (int*)alloc(N_NODES * 4);                  // doubles as cnt
    int*   csr_src = (int*)alloc((size_t)(N_EDGES + N_NODES) * 4);
    float* h       = (float*)alloc((size_t)N_NODES * 256 * 4);  // 134 MB
    float* als     = (float*)alloc((size_t)N_NODES * 4 * 4);
    float* ald     = (float*)alloc((size_t)N_NODES * 4 * 4);
    float* hbuf0   = (float*)alloc((size_t)N_NODES * 64 * 4);
    float* hbuf1   = (float*)alloc((size_t)N_NODES * 64 * 4);
    float* pooled  = (float*)alloc((size_t)NG * 3 * 64 * 4);
    (void)ws_size; (void)in_sizes; (void)n_in; (void)out_size;

    const int* srcp = ei;
    const int* dstp = ei + N_EDGES;

    init_counts<<<N_NODES / 256, 256, 0, stream>>>(cursor);
    count_edges<<<N_EDGES / 256, 256, 0, stream>>>(dstp, cursor);
    scan_kernel<<<1, 1024, 0, stream>>>(cursor, offsets);
    place_self<<<N_NODES / 256, 256, 0, stream>>>(offsets, cursor, csr_src);
    scatter_edges<<<N_EDGES / 256, 256, 0, stream>>>(srcp, dstp, cursor, csr_src);

    const float* in = x;
    for (int l = 0; l < 3; ++l) {
        if (l == 0)
            gemm_alpha<IN_DIM_, 80, 16><<<N_NODES / 64, 256, 0, stream>>>(in, W[l], asrc[l], adst[l], h, als, ald);
        else
            gemm_alpha<HID_, 64, 16><<<N_NODES / 64, 256, 0, stream>>>(in, W[l], asrc[l], adst[l], h, als, ald);
        float* ho = (l & 1) ? hbuf1 : hbuf0;
        aggregate<<<N_NODES / 4, 256, 0, stream>>>(offsets, csr_src, h, als, ald, bias[l], ho);
        pool_kernel<<<NG / 4, 256, 0, stream>>>(ho, pooled, l);
        in = ho;
    }
    final_kernel<<<NG / 4, 256, 0, stream>>>(pooled, pw, pb, out);
}

// Round 5
// 748.086 us; speedup vs baseline: 1.1921x; 1.0324x over previous
//
#include <hip/hip_runtime.h>
#include <math.h>

#define N_NODES 131072
#define N_EDGES 524288
#define IN_DIM_ 78
#define HID_ 64
#define HEADS_ 4
#define NG 4096
#define NPG 32
#define NLAYERS 3
#define NEG_SLOPE 0.2f

// ---------------- CSR build ----------------

__global__ void init_counts(int* __restrict__ cnt) {
    int n = blockIdx.x * blockDim.x + threadIdx.x;
    if (n < N_NODES) cnt[n] = 1;   // 1 = the self loop
}

__global__ void count_edges(const int* __restrict__ dst, int* __restrict__ cnt) {
    int e = blockIdx.x * blockDim.x + threadIdx.x;
    if (e < N_EDGES) atomicAdd(&cnt[dst[e]], 1);
}

// single-block exclusive scan of N_NODES counts -> offsets[N_NODES+1]
__global__ void scan_kernel(const int* __restrict__ cnt, int* __restrict__ offsets) {
    __shared__ int sums[1024];
    const int t = threadIdx.x;
    const int CHUNK = N_NODES / 1024;  // 128
    int base = t * CHUNK;
    int s = 0;
    for (int j = 0; j < CHUNK / 4; ++j) {
        int4 v = ((const int4*)(cnt + base))[j];
        s += v.x + v.y + v.z + v.w;
    }
    sums[t] = s;
    __syncthreads();
    for (int off = 1; off < 1024; off <<= 1) {
        int v = (t >= off) ? sums[t - off] : 0;
        __syncthreads();
        sums[t] += v;
        __syncthreads();
    }
    int run = (t == 0) ? 0 : sums[t - 1];
    for (int j = 0; j < CHUNK / 4; ++j) {
        int4 c = ((const int4*)(cnt + base))[j];
        int4 o;
        o.x = run; run += c.x;
        o.y = run; run += c.y;
        o.z = run; run += c.z;
        o.w = run; run += c.w;
        ((int4*)(offsets + base))[j] = o;
    }
    if (t == 1023) offsets[N_NODES] = run;   // = N_EDGES + N_NODES
}

__global__ void place_self(const int* __restrict__ offsets, int* __restrict__ cursor,
                           int* __restrict__ csr_src) {
    int n = blockIdx.x * blockDim.x + threadIdx.x;
    if (n < N_NODES) {
        int o = offsets[n];
        csr_src[o] = n;          // self loop first
        cursor[n] = o + 1;
    }
}

__global__ void scatter_edges(const int* __restrict__ src, const int* __restrict__ dst,
                              int* __restrict__ cursor, int* __restrict__ csr_src) {
    int e = blockIdx.x * blockDim.x + threadIdx.x;
    if (e < N_EDGES) {
        int d = dst[e];
        int pos = atomicAdd(&cursor[d], 1);
        csr_src[pos] = src[e];
    }
}

// ---------------- GEMM (h = A @ W) + fused alpha_src / alpha_dst ----------------
// Block: 256 threads = 16 row-groups (ty, 8 rows each) x 16 col-threads (tx).
// Tile: 128 rows x 256 cols. Thread: 8 rows x 16 cols = acc[8][4] float4,
// cols c*64 + tx*4 for c=0..3 (head = c, dims tx*4..+3).
// A stored TRANSPOSED in LDS (AsT[k][row], stride 132 -> conflict-free b128 reads);
// B staged in KB-row chunks. Per k-step per wave: 6 ds_read_b128 vs 128 FMA.
template<int K, int KPAD, int KB>
__global__ __launch_bounds__(256, 2)
void gemm_alpha(const float* __restrict__ A, const float* __restrict__ W,
                const float* __restrict__ a_src, const float* __restrict__ a_dst,
                float* __restrict__ h, float* __restrict__ als, float* __restrict__ ald) {
    constexpr int RS = 132;               // row stride: bank=(4k+r)%32 -> read conflict-free
    __shared__ float AsT[KPAD * RS];      // A transposed
    __shared__ float Bs[KB * 256];
    const int tid = threadIdx.x;
    const int tx = tid & 15;
    const int ty = tid >> 4;
    const int row0 = blockIdx.x * 128;

    // stage A transposed (coalesced global read; one-time 8-way LDS write conflict)
    {
        const float* Ab = A + (size_t)row0 * K;
        for (int i = tid; i < 128 * K; i += 256) {
            int r = i / K, k = i - r * K;
            AsT[k * RS + r] = Ab[i];
        }
        for (int i = tid; i < (KPAD - K) * 128; i += 256) {
            int k = K + (i >> 7), r = i & 127;
            AsT[k * RS + r] = 0.f;
        }
    }

    float4 acc[8][4];
    #pragma unroll
    for (int r = 0; r < 8; ++r)
        #pragma unroll
        for (int c = 0; c < 4; ++c) acc[r][c] = make_float4(0.f, 0.f, 0.f, 0.f);

    for (int kbeg = 0; kbeg < KPAD; kbeg += KB) {
        // stage B rows [kbeg, kbeg+KB) as float4 (zero-pad k >= K)
        for (int i = tid; i < KB * 64; i += 256) {
            int k = kbeg + (i >> 6);
            float4 v = make_float4(0.f, 0.f, 0.f, 0.f);
            if (k < K) v = ((const float4*)(W + (size_t)k * 256))[i & 63];
            ((float4*)Bs)[i] = v;
        }
        __syncthreads();

        #pragma unroll 2
        for (int kk = 0; kk < KB; ++kk) {
            float4 b0 = *(const float4*)&Bs[kk * 256 +   0 + tx * 4];
            float4 b1 = *(const float4*)&Bs[kk * 256 +  64 + tx * 4];
            float4 b2 = *(const float4*)&Bs[kk * 256 + 128 + tx * 4];
            float4 b3 = *(const float4*)&Bs[kk * 256 + 192 + tx * 4];
            float4 a0 = *(const float4*)&AsT[(kbeg + kk) * RS + ty * 8];
            float4 a1 = *(const float4*)&AsT[(kbeg + kk) * RS + ty * 8 + 4];
            #pragma unroll
            for (int r = 0; r < 4; ++r) {
                float a = (r == 0) ? a0.x : (r == 1) ? a0.y : (r == 2) ? a0.z : a0.w;
                acc[r][0].x += a * b0.x; acc[r][0].y += a * b0.y; acc[r][0].z += a * b0.z; acc[r][0].w += a * b0.w;
                acc[r][1].x += a * b1.x; acc[r][1].y += a * b1.y; acc[r][1].z += a * b1.z; acc[r][1].w += a * b1.w;
                acc[r][2].x += a * b2.x; acc[r][2].y += a * b2.y; acc[r][2].z += a * b2.z; acc[r][2].w += a * b2.w;
                acc[r][3].x += a * b3.x; acc[r][3].y += a * b3.y; acc[r][3].z += a * b3.z; acc[r][3].w += a * b3.w;
            }
            #pragma unroll
            for (int r = 0; r < 4; ++r) {
                float a = (r == 0) ? a1.x : (r == 1) ? a1.y : (r == 2) ? a1.z : a1.w;
                acc[r + 4][0].x += a * b0.x; acc[r + 4][0].y += a * b0.y; acc[r + 4][0].z += a * b0.z; acc[r + 4][0].w += a * b0.w;
                acc[r + 4][1].x += a * b1.x; acc[r + 4][1].y += a * b1.y; acc[r + 4][1].z += a * b1.z; acc[r + 4][1].w += a * b1.w;
                acc[r + 4][2].x += a * b2.x; acc[r + 4][2].y += a * b2.y; acc[r + 4][2].z += a * b2.z; acc[r + 4][2].w += a * b2.w;
                acc[r + 4][3].x += a * b3.x; acc[r + 4][3].y += a * b3.y; acc[r + 4][3].z += a * b3.z; acc[r + 4][3].w += a * b3.w;
            }
        }
        __syncthreads();
    }

    // epilogue: write h + fused alpha dot products (head = c, dims tx*4..+3)
    const int d4 = tx * 4;
    float4 asv[4], adv[4];
    #pragma unroll
    for (int c = 0; c < 4; ++c) {
        asv[c] = *(const float4*)&a_src[c * 64 + d4];
        adv[c] = *(const float4*)&a_dst[c * 64 + d4];
    }
    #pragma unroll
    for (int r = 0; r < 8; ++r) {
        const int row = row0 + ty * 8 + r;
        #pragma unroll
        for (int c = 0; c < 4; ++c)
            *(float4*)&h[(size_t)row * 256 + c * 64 + d4] = acc[r][c];
        #pragma unroll
        for (int c = 0; c < 4; ++c) {
            float ps = acc[r][c].x * asv[c].x + acc[r][c].y * asv[c].y
                     + acc[r][c].z * asv[c].z + acc[r][c].w * asv[c].w;
            float pd = acc[r][c].x * adv[c].x + acc[r][c].y * adv[c].y
                     + acc[r][c].z * adv[c].z + acc[r][c].w * adv[c].w;
            ps += __shfl_xor(ps, 1, 64); ps += __shfl_xor(ps, 2, 64);
            ps += __shfl_xor(ps, 4, 64); ps += __shfl_xor(ps, 8, 64);
            pd += __shfl_xor(pd, 1, 64); pd += __shfl_xor(pd, 2, 64);
            pd += __shfl_xor(pd, 4, 64); pd += __shfl_xor(pd, 8, 64);
            if (tx == 0) {
                als[row * 4 + c] = ps;
                ald[row * 4 + c] = pd;
            }
        }
    }
}

// ---------------- per-node softmax-weighted aggregation ----------------
// one wave per node; lane -> (head = lane>>4, dims d4..d4+3); 1 b128 h-load per edge.
__device__ __forceinline__ float pick4(float4 v, int idx) {
    float r = v.x;
    r = (idx == 1) ? v.y : r;
    r = (idx == 2) ? v.z : r;
    r = (idx == 3) ? v.w : r;
    return r;
}

__global__ __launch_bounds__(256)
void aggregate(const int* __restrict__ offsets, const int* __restrict__ csr_src,
               const float* __restrict__ h, const float* __restrict__ als,
               const float* __restrict__ ald, const float* __restrict__ bias,
               float* __restrict__ hout) {
    const int lane = threadIdx.x & 63;
    const int wid = __builtin_amdgcn_readfirstlane(threadIdx.x >> 6);
    const int n = blockIdx.x * 4 + wid;
    const int head = lane >> 4;
    const int d4 = (lane & 15) * 4;

    const int o0 = __builtin_amdgcn_readfirstlane(offsets[n]);
    const int o1 = __builtin_amdgcn_readfirstlane(offsets[n + 1]);

    const float ad_h = pick4(*(const float4*)&ald[n * 4], head);

    float4 acc = make_float4(0.f, 0.f, 0.f, 0.f);
    float den = 0.f;

    int i = o0;
    for (; i + 4 <= o1; i += 4) {
        int s0 = __builtin_amdgcn_readfirstlane(csr_src[i + 0]);
        int s1 = __builtin_amdgcn_readfirstlane(csr_src[i + 1]);
        int s2 = __builtin_amdgcn_readfirstlane(csr_src[i + 2]);
        int s3 = __builtin_amdgcn_readfirstlane(csr_src[i + 3]);
        float4 as0 = *(const float4*)&als[s0 * 4];
        float4 as1 = *(const float4*)&als[s1 * 4];
        float4 as2 = *(const float4*)&als[s2 * 4];
        float4 as3 = *(const float4*)&als[s3 * 4];
        float4 h0 = *(const float4*)&h[(size_t)s0 * 256 + lane * 4];
        float4 h1 = *(const float4*)&h[(size_t)s1 * 256 + lane * 4];
        float4 h2 = *(const float4*)&h[(size_t)s2 * 256 + lane * 4];
        float4 h3 = *(const float4*)&h[(size_t)s3 * 256 + lane * 4];
        float e0 = pick4(as0, head) + ad_h; e0 = e0 > 0.f ? e0 : NEG_SLOPE * e0;
        float e1 = pick4(as1, head) + ad_h; e1 = e1 > 0.f ? e1 : NEG_SLOPE * e1;
        float e2 = pick4(as2, head) + ad_h; e2 = e2 > 0.f ? e2 : NEG_SLOPE * e2;
        float e3 = pick4(as3, head) + ad_h; e3 = e3 > 0.f ? e3 : NEG_SLOPE * e3;
        float p0 = __expf(e0), p1 = __expf(e1), p2 = __expf(e2), p3 = __expf(e3);
        den += p0 + p1 + p2 + p3;
        acc.x += p0 * h0.x + p1 * h1.x + p2 * h2.x + p3 * h3.x;
        acc.y += p0 * h0.y + p1 * h1.y + p2 * h2.y + p3 * h3.y;
        acc.z += p0 * h0.z + p1 * h1.z + p2 * h2.z + p3 * h3.z;
        acc.w += p0 * h0.w + p1 * h1.w + p2 * h2.w + p3 * h3.w;
    }
    for (; i < o1; ++i) {
        int s = __builtin_amdgcn_readfirstlane(csr_src[i]);
        float4 asv = *(const float4*)&als[s * 4];
        float4 hv = *(const float4*)&h[(size_t)s * 256 + lane * 4];
        float e = pick4(asv, head) + ad_h;
        e = e > 0.f ? e : NEG_SLOPE * e;
        float p = __expf(e);
        den += p;
        acc.x += p * hv.x; acc.y += p * hv.y; acc.z += p * hv.z; acc.w += p * hv.w;
    }

    const float rden = 1.f / den;
    float c0 = acc.x * rden, c1 = acc.y * rden, c2 = acc.z * rden, c3 = acc.w * rden;
    // sum across the 4 head-groups (lanes differing in bits 4,5)
    c0 += __shfl_xor(c0, 16, 64); c0 += __shfl_xor(c0, 32, 64);
    c1 += __shfl_xor(c1, 16, 64); c1 += __shfl_xor(c1, 32, 64);
    c2 += __shfl_xor(c2, 16, 64); c2 += __shfl_xor(c2, 32, 64);
    c3 += __shfl_xor(c3, 16, 64); c3 += __shfl_xor(c3, 32, 64);

    if (lane < 16) {
        float4 bv = *(const float4*)&bias[d4];
        float v0 = 0.25f * c0 + bv.x;
        float v1 = 0.25f * c1 + bv.y;
        float v2 = 0.25f * c2 + bv.z;
        float v3 = 0.25f * c3 + bv.w;
        float4 o;
        o.x = v0 > 0.f ? v0 : 0.f;
        o.y = v1 > 0.f ? v1 : 0.f;
        o.z = v2 > 0.f ? v2 : 0.f;
        o.w = v3 > 0.f ? v3 : 0.f;
        *(float4*)&hout[(size_t)n * 64 + d4] = o;
    }
}

// ---------------- per-graph pooling (32 consecutive nodes) ----------------
__global__ __launch_bounds__(256)
void pool_kernel(const float* __restrict__ hout, float* __restrict__ pooled, int layer) {
    const int wid = threadIdx.x >> 6, lane = threadIdx.x & 63;
    const int g = blockIdx.x * 4 + wid;
    float s = 0.f;
    const float* p = &hout[(size_t)g * NPG * 64 + lane];
    #pragma unroll 8
    for (int i = 0; i < NPG; ++i) s += p[i * 64];
    pooled[(g * NLAYERS + layer) * 64 + lane] = s;
}

// ---------------- final layer-attention ----------------
__global__ __launch_bounds__(256)
void final_kernel(const float* __restrict__ pooled, const float* __restrict__ pw,
                  const float* __restrict__ pb, float* __restrict__ out) {
    const int wid = threadIdx.x >> 6, lane = threadIdx.x & 63;
    const int g = blockIdx.x * 4 + wid;
    float v0 = pooled[(g * 3 + 0) * 64 + lane];
    float v1 = pooled[(g * 3 + 1) * 64 + lane];
    float v2 = pooled[(g * 3 + 2) * 64 + lane];
    float w = pw[lane];
    float l0 = v0 * w, l1 = v1 * w, l2 = v2 * w;
    #pragma unroll
    for (int m = 1; m < 64; m <<= 1) {
        l0 += __shfl_xor(l0, m, 64);
        l1 += __shfl_xor(l1, m, 64);
        l2 += __shfl_xor(l2, m, 64);
    }
    float bb = pb[0];
    l0 += bb; l1 += bb; l2 += bb;
    float mx = fmaxf(l0, fmaxf(l1, l2));
    float e0 = __expf(l0 - mx), e1 = __expf(l1 - mx), e2 = __expf(l2 - mx);
    float inv = 1.f / (e0 + e1 + e2);
    out[(size_t)g * 64 + lane] = (v0 * e0 + v1 * e1 + v2 * e2) * inv;
}

// ---------------- launch ----------------
extern "C" void kernel_launch(void* const* d_in, const int* in_sizes, int n_in,
                              void* d_out, int out_size, void* d_ws, size_t ws_size,
                              hipStream_t stream) {
    const float* x  = (const float*)d_in[0];
    const int*   ei = (const int*)d_in[1];
    const float* W[3]    = {(const float*)d_in[3], (const float*)d_in[7],  (const float*)d_in[11]};
    const float* asrc[3] = {(const float*)d_in[4], (const float*)d_in[8],  (const float*)d_in[12]};
    const float* adst[3] = {(const float*)d_in[5], (const float*)d_in[9],  (const float*)d_in[13]};
    const float* bias[3] = {(const float*)d_in[6], (const float*)d_in[10], (const float*)d_in[14]};
    const float* pw = (const float*)d_in[15];
    const float* pb = (const float*)d_in[16];
    float* out = (float*)d_out;

    char* ws = (char*)d_ws;
    size_t off = 0;
    auto alloc = [&](size_t bytes) -> void* {
        void* p = ws + off;
        off = (off + bytes + 255) & ~(size_t)255;
        return p;
    };
    int*   offsets = (int*)alloc((N_NODES + 1) * 4);
    int*   cursor  = (int*)alloc(N_NODES * 4);                  // doubles as cnt
    int*   csr_src = (int*)alloc((size_t)(N_EDGES + N_NODES) * 4);
    float* h       = (float*)alloc((size_t)N_NODES * 256 * 4);  // 134 MB
    float* als     = (float*)alloc((size_t)N_NODES * 4 * 4);
    float* ald     = (float*)alloc((size_t)N_NODES * 4 * 4);
    float* hbuf0   = (float*)alloc((size_t)N_NODES * 64 * 4);
    float* hbuf1   = (float*)alloc((size_t)N_NODES * 64 * 4);
    float* pooled  = (float*)alloc((size_t)NG * 3 * 64 * 4);
    (void)ws_size; (void)in_sizes; (void)n_in; (void)out_size;

    const int* srcp = ei;
    const int* dstp = ei + N_EDGES;

    init_counts<<<N_NODES / 256, 256, 0, stream>>>(cursor);
    count_edges<<<N_EDGES / 256, 256, 0, stream>>>(dstp, cursor);
    scan_kernel<<<1, 1024, 0, stream>>>(cursor, offsets);
    place_self<<<N_NODES / 256, 256, 0, stream>>>(offsets, cursor, csr_src);
    scatter_edges<<<N_EDGES / 256, 256, 0, stream>>>(srcp, dstp, cursor, csr_src);

    const float* in = x;
    for (int l = 0; l < 3; ++l) {
        if (l == 0)
            gemm_alpha<IN_DIM_, 80, 16><<<N_NODES / 128, 256, 0, stream>>>(in, W[l], asrc[l], adst[l], h, als, ald);
        else
            gemm_alpha<HID_, 64, 16><<<N_NODES / 128, 256, 0, stream>>>(in, W[l], asrc[l], adst[l], h, als, ald);
        float* ho = (l & 1) ? hbuf1 : hbuf0;
        aggregate<<<N_NODES / 4, 256, 0, stream>>>(offsets, csr_src, h, als, ald, bias[l], ho);
        pool_kernel<<<NG / 4, 256, 0, stream>>>(ho, pooled, l);
        in = ho;
    }
    final_kernel<<<NG / 4, 256, 0, stream>>>(pooled, pw, pb, out);
}

// Round 6
// 618.410 us; speedup vs baseline: 1.4421x; 1.2097x over previous
//
#include <hip/hip_runtime.h>
#include <math.h>

#define N_NODES 131072
#define N_EDGES 524288
#define IN_DIM_ 78
#define HID_ 64
#define HEADS_ 4
#define NG 4096
#define NPG 32
#define NLAYERS 3
#define NEG_SLOPE 0.2f

// bf16 helpers (storage type for h only; all math in f32)
__device__ __forceinline__ unsigned short f2bf(float f) {
    unsigned int u = __float_as_uint(f);
    u = (u + 0x7FFF + ((u >> 16) & 1)) >> 16;   // round-to-nearest-even
    return (unsigned short)u;
}
__device__ __forceinline__ float bf2f(unsigned short u) {
    return __uint_as_float(((unsigned int)u) << 16);
}

// ---------------- CSR build ----------------

__global__ void init_counts(int* __restrict__ cnt) {
    int n = blockIdx.x * blockDim.x + threadIdx.x;
    if (n < N_NODES) cnt[n] = 1;   // 1 = the self loop
}

__global__ void count_edges(const int* __restrict__ dst, int* __restrict__ cnt) {
    int e = blockIdx.x * blockDim.x + threadIdx.x;
    if (e < N_EDGES) atomicAdd(&cnt[dst[e]], 1);
}

// single-block exclusive scan of N_NODES counts -> offsets[N_NODES+1]
__global__ void scan_kernel(const int* __restrict__ cnt, int* __restrict__ offsets) {
    __shared__ int sums[1024];
    const int t = threadIdx.x;
    const int CHUNK = N_NODES / 1024;  // 128
    int base = t * CHUNK;
    int s = 0;
    for (int j = 0; j < CHUNK / 4; ++j) {
        int4 v = ((const int4*)(cnt + base))[j];
        s += v.x + v.y + v.z + v.w;
    }
    sums[t] = s;
    __syncthreads();
    for (int off = 1; off < 1024; off <<= 1) {
        int v = (t >= off) ? sums[t - off] : 0;
        __syncthreads();
        sums[t] += v;
        __syncthreads();
    }
    int run = (t == 0) ? 0 : sums[t - 1];
    for (int j = 0; j < CHUNK / 4; ++j) {
        int4 c = ((const int4*)(cnt + base))[j];
        int4 o;
        o.x = run; run += c.x;
        o.y = run; run += c.y;
        o.z = run; run += c.z;
        o.w = run; run += c.w;
        ((int4*)(offsets + base))[j] = o;
    }
    if (t == 1023) offsets[N_NODES] = run;   // = N_EDGES + N_NODES
}

__global__ void place_self(const int* __restrict__ offsets, int* __restrict__ cursor,
                           int* __restrict__ csr_src) {
    int n = blockIdx.x * blockDim.x + threadIdx.x;
    if (n < N_NODES) {
        int o = offsets[n];
        csr_src[o] = n;          // self loop first
        cursor[n] = o + 1;
    }
}

__global__ void scatter_edges(const int* __restrict__ src, const int* __restrict__ dst,
                              int* __restrict__ cursor, int* __restrict__ csr_src) {
    int e = blockIdx.x * blockDim.x + threadIdx.x;
    if (e < N_EDGES) {
        int d = dst[e];
        int pos = atomicAdd(&cursor[d], 1);
        csr_src[pos] = src[e];
    }
}

// ---------------- GEMM (h = A @ W) + fused alpha_src / alpha_dst ----------------
// Block: 256 threads = 8 row-groups (ty) x 32 col-threads (tx).
// Tile: 64 rows x 256 cols. Thread: 8 rows x 8 cols (cols tx*4 and 128+tx*4).
// A transposed in LDS (AsT[k][r], stride 68): A frag = 2 x ds_read_b128 broadcasts.
// B single-buffered in LDS, next chunk prefetched into REGISTERS during the
// k-loop (async-stage split) so global latency hides under the FMAs.
// LDS = 21.8 + 16 KB -> 4 blocks/CU. h written as bf16.
template<int K, int KPAD, int KB>
__global__ __launch_bounds__(256, 4)
void gemm_alpha(const float* __restrict__ A, const float* __restrict__ W,
                const float* __restrict__ a_src, const float* __restrict__ a_dst,
                unsigned short* __restrict__ h, float* __restrict__ als, float* __restrict__ ald) {
    constexpr int RS = 68;                 // AsT row stride (floats)
    constexpr int NCH = KPAD / KB;
    __shared__ float AsT[KPAD * RS];
    __shared__ float Bs[KB * 256];
    const int tid = threadIdx.x;
    const int tx = tid & 31;
    const int ty = tid >> 5;
    const int row0 = blockIdx.x * 64;

    // stage A transposed (one-time; write conflicts are negligible)
    {
        const float* Ab = A + (size_t)row0 * K;
        for (int i = tid; i < 64 * K; i += 256) {
            int r = i / K, k = i - r * K;
            AsT[k * RS + r] = Ab[i];
        }
        for (int i = tid; i < (KPAD - K) * 64; i += 256) {
            int k = K + (i >> 6), r = i & 63;
            AsT[k * RS + r] = 0.f;
        }
    }

    // prefetch registers for B chunk staging (4 float4 per thread per chunk)
    float4 nb0, nb1, nb2, nb3;
    auto loadB = [&](int ch) {
        const int kbeg = ch * KB;
        int i0 = tid, i1 = tid + 256, i2 = tid + 512, i3 = tid + 768;
        int k0 = kbeg + (i0 >> 6), k1 = kbeg + (i1 >> 6), k2 = kbeg + (i2 >> 6), k3 = kbeg + (i3 >> 6);
        const float4* Wf4 = (const float4*)W;
        nb0 = (k0 < K) ? Wf4[(size_t)k0 * 64 + (i0 & 63)] : make_float4(0.f, 0.f, 0.f, 0.f);
        nb1 = (k1 < K) ? Wf4[(size_t)k1 * 64 + (i1 & 63)] : make_float4(0.f, 0.f, 0.f, 0.f);
        nb2 = (k2 < K) ? Wf4[(size_t)k2 * 64 + (i2 & 63)] : make_float4(0.f, 0.f, 0.f, 0.f);
        nb3 = (k3 < K) ? Wf4[(size_t)k3 * 64 + (i3 & 63)] : make_float4(0.f, 0.f, 0.f, 0.f);
    };
    auto writeB = [&]() {
        ((float4*)Bs)[tid]       = nb0;
        ((float4*)Bs)[tid + 256] = nb1;
        ((float4*)Bs)[tid + 512] = nb2;
        ((float4*)Bs)[tid + 768] = nb3;
    };

    float4 acc0[8], acc1[8];
    #pragma unroll
    for (int r = 0; r < 8; ++r) {
        acc0[r] = make_float4(0.f, 0.f, 0.f, 0.f);
        acc1[r] = make_float4(0.f, 0.f, 0.f, 0.f);
    }

    loadB(0);
    writeB();
    __syncthreads();   // AsT + Bs chunk 0 ready

    for (int ch = 0; ch < NCH; ++ch) {
        if (ch + 1 < NCH) loadB(ch + 1);   // issue global loads; consumed after k-loop

        #pragma unroll 4
        for (int kk = 0; kk < KB; ++kk) {
            float4 b0 = *(const float4*)&Bs[kk * 256 + tx * 4];
            float4 b1 = *(const float4*)&Bs[kk * 256 + 128 + tx * 4];
            const float* ap = &AsT[(ch * KB + kk) * RS + ty * 8];
            float4 a0 = *(const float4*)ap;
            float4 a1 = *(const float4*)(ap + 4);
            #pragma unroll
            for (int r = 0; r < 4; ++r) {
                float a = (r == 0) ? a0.x : (r == 1) ? a0.y : (r == 2) ? a0.z : a0.w;
                acc0[r].x += a * b0.x; acc0[r].y += a * b0.y; acc0[r].z += a * b0.z; acc0[r].w += a * b0.w;
                acc1[r].x += a * b1.x; acc1[r].y += a * b1.y; acc1[r].z += a * b1.z; acc1[r].w += a * b1.w;
            }
            #pragma unroll
            for (int r = 0; r < 4; ++r) {
                float a = (r == 0) ? a1.x : (r == 1) ? a1.y : (r == 2) ? a1.z : a1.w;
                acc0[r + 4].x += a * b0.x; acc0[r + 4].y += a * b0.y; acc0[r + 4].z += a * b0.z; acc0[r + 4].w += a * b0.w;
                acc1[r + 4].x += a * b1.x; acc1[r + 4].y += a * b1.y; acc1[r + 4].z += a * b1.z; acc1[r + 4].w += a * b1.w;
            }
        }

        if (ch + 1 < NCH) {
            __syncthreads();   // everyone done reading Bs
            writeB();
            __syncthreads();   // Bs chunk ch+1 ready
        }
    }

    // epilogue: write h (bf16) + fused alpha dot products (f32 from f32 acc).
    // group0 cols tx*4 -> head h0 = tx>>4 (0/1); group1 cols 128+tx*4 -> head h0+2.
    const int h0 = tx >> 4;
    const int d4 = (tx & 15) * 4;
    float4 as0 = *(const float4*)&a_src[h0 * 64 + d4];
    float4 ad0 = *(const float4*)&a_dst[h0 * 64 + d4];
    float4 as1 = *(const float4*)&a_src[(h0 + 2) * 64 + d4];
    float4 ad1 = *(const float4*)&a_dst[(h0 + 2) * 64 + d4];
    #pragma unroll
    for (int r = 0; r < 8; ++r) {
        const int row = row0 + ty * 8 + r;
        ushort4 o0, o1;
        o0.x = f2bf(acc0[r].x); o0.y = f2bf(acc0[r].y); o0.z = f2bf(acc0[r].z); o0.w = f2bf(acc0[r].w);
        o1.x = f2bf(acc1[r].x); o1.y = f2bf(acc1[r].y); o1.z = f2bf(acc1[r].z); o1.w = f2bf(acc1[r].w);
        *(ushort4*)&h[(size_t)row * 256 + tx * 4]       = o0;
        *(ushort4*)&h[(size_t)row * 256 + 128 + tx * 4] = o1;
        float ps0 = acc0[r].x * as0.x + acc0[r].y * as0.y + acc0[r].z * as0.z + acc0[r].w * as0.w;
        float pd0 = acc0[r].x * ad0.x + acc0[r].y * ad0.y + acc0[r].z * ad0.z + acc0[r].w * ad0.w;
        float ps1 = acc1[r].x * as1.x + acc1[r].y * as1.y + acc1[r].z * as1.z + acc1[r].w * as1.w;
        float pd1 = acc1[r].x * ad1.x + acc1[r].y * ad1.y + acc1[r].z * ad1.z + acc1[r].w * ad1.w;
        #pragma unroll
        for (int m = 1; m < 16; m <<= 1) {
            ps0 += __shfl_xor(ps0, m, 64);
            pd0 += __shfl_xor(pd0, m, 64);
            ps1 += __shfl_xor(ps1, m, 64);
            pd1 += __shfl_xor(pd1, m, 64);
        }
        if ((tx & 15) == 0) {
            als[row * 4 + h0]     = ps0;
            ald[row * 4 + h0]     = pd0;
            als[row * 4 + h0 + 2] = ps1;
            ald[row * 4 + h0 + 2] = pd1;
        }
    }
}

// ---------------- per-node softmax-weighted aggregation ----------------
// one wave per node; lane -> (head = lane>>4, dims d4..d4+3); h is bf16:
// per edge the wave reads one 512B row (ushort4 per lane, coalesced).
__device__ __forceinline__ float pick4(float4 v, int idx) {
    float r = v.x;
    r = (idx == 1) ? v.y : r;
    r = (idx == 2) ? v.z : r;
    r = (idx == 3) ? v.w : r;
    return r;
}

__global__ __launch_bounds__(256)
void aggregate(const int* __restrict__ offsets, const int* __restrict__ csr_src,
               const unsigned short* __restrict__ h, const float* __restrict__ als,
               const float* __restrict__ ald, const float* __restrict__ bias,
               float* __restrict__ hout) {
    const int lane = threadIdx.x & 63;
    const int wid = __builtin_amdgcn_readfirstlane(threadIdx.x >> 6);
    const int n = blockIdx.x * 4 + wid;
    const int head = lane >> 4;
    const int d4 = (lane & 15) * 4;

    const int o0 = __builtin_amdgcn_readfirstlane(offsets[n]);
    const int o1 = __builtin_amdgcn_readfirstlane(offsets[n + 1]);

    const float ad_h = pick4(*(const float4*)&ald[n * 4], head);

    float4 acc = make_float4(0.f, 0.f, 0.f, 0.f);
    float den = 0.f;

    int i = o0;
    for (; i + 4 <= o1; i += 4) {
        int s0 = __builtin_amdgcn_readfirstlane(csr_src[i + 0]);
        int s1 = __builtin_amdgcn_readfirstlane(csr_src[i + 1]);
        int s2 = __builtin_amdgcn_readfirstlane(csr_src[i + 2]);
        int s3 = __builtin_amdgcn_readfirstlane(csr_src[i + 3]);
        float4 as0 = *(const float4*)&als[s0 * 4];
        float4 as1 = *(const float4*)&als[s1 * 4];
        float4 as2 = *(const float4*)&als[s2 * 4];
        float4 as3 = *(const float4*)&als[s3 * 4];
        ushort4 u0 = ((const ushort4*)(h + (size_t)s0 * 256))[lane];
        ushort4 u1 = ((const ushort4*)(h + (size_t)s1 * 256))[lane];
        ushort4 u2 = ((const ushort4*)(h + (size_t)s2 * 256))[lane];
        ushort4 u3 = ((const ushort4*)(h + (size_t)s3 * 256))[lane];
        float e0 = pick4(as0, head) + ad_h; e0 = e0 > 0.f ? e0 : NEG_SLOPE * e0;
        float e1 = pick4(as1, head) + ad_h; e1 = e1 > 0.f ? e1 : NEG_SLOPE * e1;
        float e2 = pick4(as2, head) + ad_h; e2 = e2 > 0.f ? e2 : NEG_SLOPE * e2;
        float e3 = pick4(as3, head) + ad_h; e3 = e3 > 0.f ? e3 : NEG_SLOPE * e3;
        float p0 = __expf(e0), p1 = __expf(e1), p2 = __expf(e2), p3 = __expf(e3);
        den += p0 + p1 + p2 + p3;
        acc.x += p0 * bf2f(u0.x) + p1 * bf2f(u1.x) + p2 * bf2f(u2.x) + p3 * bf2f(u3.x);
        acc.y += p0 * bf2f(u0.y) + p1 * bf2f(u1.y) + p2 * bf2f(u2.y) + p3 * bf2f(u3.y);
        acc.z += p0 * bf2f(u0.z) + p1 * bf2f(u1.z) + p2 * bf2f(u2.z) + p3 * bf2f(u3.z);
        acc.w += p0 * bf2f(u0.w) + p1 * bf2f(u1.w) + p2 * bf2f(u2.w) + p3 * bf2f(u3.w);
    }
    for (; i < o1; ++i) {
        int s = __builtin_amdgcn_readfirstlane(csr_src[i]);
        float4 asv = *(const float4*)&als[s * 4];
        ushort4 uv = ((const ushort4*)(h + (size_t)s * 256))[lane];
        float e = pick4(asv, head) + ad_h;
        e = e > 0.f ? e : NEG_SLOPE * e;
        float p = __expf(e);
        den += p;
        acc.x += p * bf2f(uv.x); acc.y += p * bf2f(uv.y);
        acc.z += p * bf2f(uv.z); acc.w += p * bf2f(uv.w);
    }

    const float rden = 1.f / den;
    float c0 = acc.x * rden, c1 = acc.y * rden, c2 = acc.z * rden, c3 = acc.w * rden;
    // sum across the 4 head-groups (lanes differing in bits 4,5)
    c0 += __shfl_xor(c0, 16, 64); c0 += __shfl_xor(c0, 32, 64);
    c1 += __shfl_xor(c1, 16, 64); c1 += __shfl_xor(c1, 32, 64);
    c2 += __shfl_xor(c2, 16, 64); c2 += __shfl_xor(c2, 32, 64);
    c3 += __shfl_xor(c3, 16, 64); c3 += __shfl_xor(c3, 32, 64);

    if (lane < 16) {
        float4 bv = *(const float4*)&bias[d4];
        float v0 = 0.25f * c0 + bv.x;
        float v1 = 0.25f * c1 + bv.y;
        float v2 = 0.25f * c2 + bv.z;
        float v3 = 0.25f * c3 + bv.w;
        float4 o;
        o.x = v0 > 0.f ? v0 : 0.f;
        o.y = v1 > 0.f ? v1 : 0.f;
        o.z = v2 > 0.f ? v2 : 0.f;
        o.w = v3 > 0.f ? v3 : 0.f;
        *(float4*)&hout[(size_t)n * 64 + d4] = o;
    }
}

// ---------------- per-graph pooling (32 consecutive nodes) ----------------
__global__ __launch_bounds__(256)
void pool_kernel(const float* __restrict__ hout, float* __restrict__ pooled, int layer) {
    const int wid = threadIdx.x >> 6, lane = threadIdx.x & 63;
    const int g = blockIdx.x * 4 + wid;
    float s = 0.f;
    const float* p = &hout[(size_t)g * NPG * 64 + lane];
    #pragma unroll 8
    for (int i = 0; i < NPG; ++i) s += p[i * 64];
    pooled[(g * NLAYERS + layer) * 64 + lane] = s;
}

// ---------------- final layer-attention ----------------
__global__ __launch_bounds__(256)
void final_kernel(const float* __restrict__ pooled, const float* __restrict__ pw,
                  const float* __restrict__ pb, float* __restrict__ out) {
    const int wid = threadIdx.x >> 6, lane = threadIdx.x & 63;
    const int g = blockIdx.x * 4 + wid;
    float v0 = pooled[(g * 3 + 0) * 64 + lane];
    float v1 = pooled[(g * 3 + 1) * 64 + lane];
    float v2 = pooled[(g * 3 + 2) * 64 + lane];
    float w = pw[lane];
    float l0 = v0 * w, l1 = v1 * w, l2 = v2 * w;
    #pragma unroll
    for (int m = 1; m < 64; m <<= 1) {
        l0 += __shfl_xor(l0, m, 64);
        l1 += __shfl_xor(l1, m, 64);
        l2 += __shfl_xor(l2, m, 64);
    }
    float bb = pb[0];
    l0 += bb; l1 += bb; l2 += bb;
    float mx = fmaxf(l0, fmaxf(l1, l2));
    float e0 = __expf(l0 - mx), e1 = __expf(l1 - mx), e2 = __expf(l2 - mx);
    float inv = 1.f / (e0 + e1 + e2);
    out[(size_t)g * 64 + lane] = (v0 * e0 + v1 * e1 + v2 * e2) * inv;
}

// ---------------- launch ----------------
extern "C" void kernel_launch(void* const* d_in, const int* in_sizes, int n_in,
                              void* d_out, int out_size, void* d_ws, size_t ws_size,
                              hipStream_t stream) {
    const float* x  = (const float*)d_in[0];
    const int*   ei = (const int*)d_in[1];
    const float* W[3]    = {(const float*)d_in[3], (const float*)d_in[7],  (const float*)d_in[11]};
    const float* asrc[3] = {(const float*)d_in[4], (const float*)d_in[8],  (const float*)d_in[12]};
    const float* adst[3] = {(const float*)d_in[5], (const float*)d_in[9],  (const float*)d_in[13]};
    const float* bias[3] = {(const float*)d_in[6], (const float*)d_in[10], (const float*)d_in[14]};
    const float* pw = (const float*)d_in[15];
    const float* pb = (const float*)d_in[16];
    float* out = (float*)d_out;

    char* ws = (char*)d_ws;
    size_t off = 0;
    auto alloc = [&](size_t bytes) -> void* {
        void* p = ws + off;
        off = (off + bytes + 255) & ~(size_t)255;
        return p;
    };
    int*   offsets = (int*)alloc((N_NODES + 1) * 4);
    int*   cursor  = (int*)alloc(N_NODES * 4);                  // doubles as cnt
    int*   csr_src = (int*)alloc((size_t)(N_EDGES + N_NODES) * 4);
    unsigned short* h = (unsigned short*)alloc((size_t)N_NODES * 256 * 2);  // 67 MB bf16
    float* als     = (float*)alloc((size_t)N_NODES * 4 * 4);
    float* ald     = (float*)alloc((size_t)N_NODES * 4 * 4);
    float* hbuf0   = (float*)alloc((size_t)N_NODES * 64 * 4);
    float* hbuf1   = (float*)alloc((size_t)N_NODES * 64 * 4);
    float* pooled  = (float*)alloc((size_t)NG * 3 * 64 * 4);
    (void)ws_size; (void)in_sizes; (void)n_in; (void)out_size;

    const int* srcp = ei;
    const int* dstp = ei + N_EDGES;

    init_counts<<<N_NODES / 256, 256, 0, stream>>>(cursor);
    count_edges<<<N_EDGES / 256, 256, 0, stream>>>(dstp, cursor);
    scan_kernel<<<1, 1024, 0, stream>>>(cursor, offsets);
    place_self<<<N_NODES / 256, 256, 0, stream>>>(offsets, cursor, csr_src);
    scatter_edges<<<N_EDGES / 256, 256, 0, stream>>>(srcp, dstp, cursor, csr_src);

    const float* in = x;
    for (int l = 0; l < 3; ++l) {
        if (l == 0)
            gemm_alpha<IN_DIM_, 80, 16><<<N_NODES / 64, 256, 0, stream>>>(in, W[l], asrc[l], adst[l], h, als, ald);
        else
            gemm_alpha<HID_, 64, 16><<<N_NODES / 64, 256, 0, stream>>>(in, W[l], asrc[l], adst[l], h, als, ald);
        float* ho = (l & 1) ? hbuf1 : hbuf0;
        aggregate<<<N_NODES / 4, 256, 0, stream>>>(offsets, csr_src, h, als, ald, bias[l], ho);
        pool_kernel<<<NG / 4, 256, 0, stream>>>(ho, pooled, l);
        in = ho;
    }
    final_kernel<<<NG / 4, 256, 0, stream>>>(pooled, pw, pb, out);
}

// Round 7
// 570.137 us; speedup vs baseline: 1.5642x; 1.0847x over previous
//
#include <hip/hip_runtime.h>
#include <math.h>

#define N_NODES 131072
#define N_EDGES 524288
#define IN_DIM_ 78
#define HID_ 64
#define HEADS_ 4
#define NG 4096
#define NPG 32
#define NLAYERS 3
#define NEG_SLOPE 0.2f

typedef __attribute__((ext_vector_type(8))) short bf16x8;
typedef __attribute__((ext_vector_type(4))) float f32x4;

// bf16 helpers (round-to-nearest-even)
__device__ __forceinline__ unsigned short f2bf(float f) {
    unsigned int u = __float_as_uint(f);
    u = (u + 0x7FFF + ((u >> 16) & 1)) >> 16;
    return (unsigned short)u;
}
__device__ __forceinline__ float bf2f(unsigned short u) {
    return __uint_as_float(((unsigned int)u) << 16);
}

// ---------------- CSR build ----------------

__global__ void init_counts(int* __restrict__ cnt) {
    int n = blockIdx.x * blockDim.x + threadIdx.x;
    if (n < N_NODES) cnt[n] = 1;   // 1 = the self loop
}

__global__ void count_edges(const int* __restrict__ dst, int* __restrict__ cnt) {
    int e = blockIdx.x * blockDim.x + threadIdx.x;
    if (e < N_EDGES) atomicAdd(&cnt[dst[e]], 1);
}

__global__ void scan_kernel(const int* __restrict__ cnt, int* __restrict__ offsets) {
    __shared__ int sums[1024];
    const int t = threadIdx.x;
    const int CHUNK = N_NODES / 1024;  // 128
    int base = t * CHUNK;
    int s = 0;
    for (int j = 0; j < CHUNK / 4; ++j) {
        int4 v = ((const int4*)(cnt + base))[j];
        s += v.x + v.y + v.z + v.w;
    }
    sums[t] = s;
    __syncthreads();
    for (int off = 1; off < 1024; off <<= 1) {
        int v = (t >= off) ? sums[t - off] : 0;
        __syncthreads();
        sums[t] += v;
        __syncthreads();
    }
    int run = (t == 0) ? 0 : sums[t - 1];
    for (int j = 0; j < CHUNK / 4; ++j) {
        int4 c = ((const int4*)(cnt + base))[j];
        int4 o;
        o.x = run; run += c.x;
        o.y = run; run += c.y;
        o.z = run; run += c.z;
        o.w = run; run += c.w;
        ((int4*)(offsets + base))[j] = o;
    }
    if (t == 1023) offsets[N_NODES] = run;
}

__global__ void place_self(const int* __restrict__ offsets, int* __restrict__ cursor,
                           int* __restrict__ csr_src) {
    int n = blockIdx.x * blockDim.x + threadIdx.x;
    if (n < N_NODES) {
        int o = offsets[n];
        csr_src[o] = n;
        cursor[n] = o + 1;
    }
}

__global__ void scatter_edges(const int* __restrict__ src, const int* __restrict__ dst,
                              int* __restrict__ cursor, int* __restrict__ csr_src) {
    int e = blockIdx.x * blockDim.x + threadIdx.x;
    if (e < N_EDGES) {
        int d = dst[e];
        int pos = atomicAdd(&cursor[d], 1);
        csr_src[pos] = src[e];
    }
}

// ---------------- W split/transpose prep ----------------
// W [K][256] f32 -> WtH/WtL [256][96] bf16 (zero-padded k>=K)
__global__ void wsplit(const float* __restrict__ W, int K,
                       unsigned short* __restrict__ WtH, unsigned short* __restrict__ WtL) {
    int k = blockIdx.x;        // 0..95
    int col = threadIdx.x;     // 0..255
    float w = (k < K) ? W[k * 256 + col] : 0.f;
    unsigned short hi = f2bf(w);
    unsigned short lo = f2bf(w - bf2f(hi));
    WtH[col * 96 + k] = hi;
    WtL[col * 96 + k] = lo;
}

// ---------------- MFMA GEMM (h = A @ W, bf16x3 split) + fused alphas ----------------
// Block: 256 threads = 4 waves. Tile: 64 rows x 256 cols.
// Wave w: rows (w>>1)*32..+31 (2 row-tiles), cols (w&1)*128..+127 (8 col-tiles).
// A split hi/lo in LDS [64][104] bf16; W chunk (32 k) staged in ONE [256][40]
// buffer: hi-pass (Ah*Bh + Al*Bh) then lo-pass (Ah*Bl). Reg-prefetch staging.
template<int NCH, int K>
__global__ __launch_bounds__(256, 3)
void gemm_mfma(const float* __restrict__ A,
               const unsigned short* __restrict__ WtH,
               const unsigned short* __restrict__ WtL,
               const float* __restrict__ a_src, const float* __restrict__ a_dst,
               unsigned short* __restrict__ h, float* __restrict__ als, float* __restrict__ ald) {
    constexpr int AS = 104;            // As row stride (ushort); 208B -> 2-way max aliasing
    constexpr int BS = 40;             // Bst col stride (ushort); 80B  -> 2-way max aliasing
    constexpr int KP = NCH * 32;
    __shared__ __align__(16) unsigned short AsH[64 * AS];
    __shared__ __align__(16) unsigned short AsL[64 * AS];
    __shared__ __align__(16) unsigned short Bst[256 * BS];
    const int tid = threadIdx.x;
    const int w = tid >> 6;
    const int lane = tid & 63;
    const int li = lane & 15, lg = lane >> 4;
    const int row0 = blockIdx.x * 64;
    const int r0 = (w >> 1) * 32, c0 = (w & 1) * 128;

    // ---- stage A split hi/lo (K even -> float2 / ushort2 moves) ----
    {
        const float2* Ab = (const float2*)(A + (size_t)row0 * K);
        constexpr int NF2 = 64 * K / 2;
        for (int i = tid; i < NF2; i += 256) {
            float2 v = Ab[i];
            int row = (2 * i) / K, k = (2 * i) % K;
            unsigned short hx = f2bf(v.x);
            unsigned short lx = f2bf(v.x - bf2f(hx));
            unsigned short hy = f2bf(v.y);
            unsigned short ly = f2bf(v.y - bf2f(hy));
            ushort2 hv; hv.x = hx; hv.y = hy;
            ushort2 lv; lv.x = lx; lv.y = ly;
            *(ushort2*)&AsH[row * AS + k] = hv;
            *(ushort2*)&AsL[row * AS + k] = lv;
        }
        if constexpr (KP > K) {
            constexpr int PAD2 = (KP - K) / 2;
            for (int i = tid; i < 64 * PAD2; i += 256) {
                int row = i / PAD2, j = i - row * PAD2;
                int k = K + 2 * j;
                *(unsigned int*)&AsH[row * AS + k] = 0u;
                *(unsigned int*)&AsL[row * AS + k] = 0u;
            }
        }
    }

    // B chunk staging via registers (8 x ushort4 per thread)
    ushort4 breg[8];
    auto loadB = [&](const unsigned short* __restrict__ Wt, int ch) {
        #pragma unroll
        for (int m = 0; m < 8; ++m) {
            int idx = m * 256 + tid;
            int col = idx >> 3, k4 = idx & 7;
            breg[m] = *(const ushort4*)&Wt[col * 96 + ch * 32 + k4 * 4];
        }
    };
    auto writeB = [&]() {
        #pragma unroll
        for (int m = 0; m < 8; ++m) {
            int idx = m * 256 + tid;
            int col = idx >> 3, k4 = idx & 7;
            *(ushort4*)&Bst[col * BS + k4 * 4] = breg[m];
        }
    };

    f32x4 acc[2][8];
    #pragma unroll
    for (int rt = 0; rt < 2; ++rt)
        #pragma unroll
        for (int ct = 0; ct < 8; ++ct)
            acc[rt][ct] = (f32x4){0.f, 0.f, 0.f, 0.f};

    loadB(WtH, 0);
    writeB();
    __syncthreads();   // As + Bst(hi,0) ready

    #pragma unroll
    for (int ch = 0; ch < NCH; ++ch) {
        bf16x8 ah[2], al[2];
        #pragma unroll
        for (int rt = 0; rt < 2; ++rt) {
            int aoff = (r0 + rt * 16 + li) * AS + ch * 32 + lg * 8;
            ah[rt] = *(const bf16x8*)&AsH[aoff];
            al[rt] = *(const bf16x8*)&AsL[aoff];
        }
        loadB(WtL, ch);            // prefetch lo while computing on hi
        #pragma unroll
        for (int ct = 0; ct < 8; ++ct) {
            bf16x8 bh = *(const bf16x8*)&Bst[(c0 + ct * 16 + li) * BS + lg * 8];
            #pragma unroll
            for (int rt = 0; rt < 2; ++rt) {
                acc[rt][ct] = __builtin_amdgcn_mfma_f32_16x16x32_bf16(ah[rt], bh, acc[rt][ct], 0, 0, 0);
                acc[rt][ct] = __builtin_amdgcn_mfma_f32_16x16x32_bf16(al[rt], bh, acc[rt][ct], 0, 0, 0);
            }
        }
        __syncthreads();
        writeB();                  // lo -> Bst
        __syncthreads();
        if (ch + 1 < NCH) loadB(WtH, ch + 1);   // prefetch next hi
        #pragma unroll
        for (int ct = 0; ct < 8; ++ct) {
            bf16x8 bl = *(const bf16x8*)&Bst[(c0 + ct * 16 + li) * BS + lg * 8];
            #pragma unroll
            for (int rt = 0; rt < 2; ++rt)
                acc[rt][ct] = __builtin_amdgcn_mfma_f32_16x16x32_bf16(ah[rt], bl, acc[rt][ct], 0, 0, 0);
        }
        if (ch + 1 < NCH) {
            __syncthreads();
            writeB();              // next hi -> Bst
            __syncthreads();
        }
    }

    // ---- epilogue: h (bf16) via lane-paired u32 stores + fused alpha dots ----
    // D layout per tile: col = li, row = lg*4 + reg (verified m89/m91).
    #pragma unroll
    for (int rt = 0; rt < 2; ++rt) {
        #pragma unroll
        for (int ct = 0; ct < 8; ++ct) {
            #pragma unroll
            for (int reg = 0; reg < 4; ++reg) {
                int row = row0 + r0 + rt * 16 + lg * 4 + reg;
                int col = c0 + ct * 16 + li;
                unsigned int v = f2bf(acc[rt][ct][reg]);
                unsigned int pv = (unsigned int)__shfl_xor((int)v, 1, 64) & 0xFFFFu;
                if ((li & 1) == 0)
                    *(unsigned int*)&h[(size_t)row * 256 + col] = v | (pv << 16);
            }
        }
    }

    float as_v[8], ad_v[8];
    #pragma unroll
    for (int ct = 0; ct < 8; ++ct) {
        int ghead = (w & 1) * 2 + (ct >> 2);
        as_v[ct] = a_src[ghead * 64 + (ct & 3) * 16 + li];
        ad_v[ct] = a_dst[ghead * 64 + (ct & 3) * 16 + li];
    }
    #pragma unroll
    for (int rt = 0; rt < 2; ++rt) {
        #pragma unroll
        for (int hl = 0; hl < 2; ++hl) {
            #pragma unroll
            for (int reg = 0; reg < 4; ++reg) {
                float ps = 0.f, pd = 0.f;
                #pragma unroll
                for (int c4 = 0; c4 < 4; ++c4) {
                    int ct = hl * 4 + c4;
                    ps += acc[rt][ct][reg] * as_v[ct];
                    pd += acc[rt][ct][reg] * ad_v[ct];
                }
                ps += __shfl_xor(ps, 1, 64); ps += __shfl_xor(ps, 2, 64);
                ps += __shfl_xor(ps, 4, 64); ps += __shfl_xor(ps, 8, 64);
                pd += __shfl_xor(pd, 1, 64); pd += __shfl_xor(pd, 2, 64);
                pd += __shfl_xor(pd, 4, 64); pd += __shfl_xor(pd, 8, 64);
                if (li == 0) {
                    int row = row0 + r0 + rt * 16 + lg * 4 + reg;
                    int ghead = (w & 1) * 2 + hl;
                    als[row * 4 + ghead] = ps;
                    ald[row * 4 + ghead] = pd;
                }
            }
        }
    }
}

// ---------------- per-node softmax-weighted aggregation ----------------
__device__ __forceinline__ float pick4(float4 v, int idx) {
    float r = v.x;
    r = (idx == 1) ? v.y : r;
    r = (idx == 2) ? v.z : r;
    r = (idx == 3) ? v.w : r;
    return r;
}

__global__ __launch_bounds__(256)
void aggregate(const int* __restrict__ offsets, const int* __restrict__ csr_src,
               const unsigned short* __restrict__ h, const float* __restrict__ als,
               const float* __restrict__ ald, const float* __restrict__ bias,
               float* __restrict__ hout) {
    const int lane = threadIdx.x & 63;
    const int wid = __builtin_amdgcn_readfirstlane(threadIdx.x >> 6);
    const int n = blockIdx.x * 4 + wid;
    const int head = lane >> 4;
    const int d4 = (lane & 15) * 4;

    const int o0 = __builtin_amdgcn_readfirstlane(offsets[n]);
    const int o1 = __builtin_amdgcn_readfirstlane(offsets[n + 1]);

    const float ad_h = pick4(*(const float4*)&ald[n * 4], head);

    float4 acc = make_float4(0.f, 0.f, 0.f, 0.f);
    float den = 0.f;

    int i = o0;
    for (; i + 4 <= o1; i += 4) {
        int s0 = __builtin_amdgcn_readfirstlane(csr_src[i + 0]);
        int s1 = __builtin_amdgcn_readfirstlane(csr_src[i + 1]);
        int s2 = __builtin_amdgcn_readfirstlane(csr_src[i + 2]);
        int s3 = __builtin_amdgcn_readfirstlane(csr_src[i + 3]);
        float4 as0 = *(const float4*)&als[s0 * 4];
        float4 as1 = *(const float4*)&als[s1 * 4];
        float4 as2 = *(const float4*)&als[s2 * 4];
        float4 as3 = *(const float4*)&als[s3 * 4];
        ushort4 u0 = ((const ushort4*)(h + (size_t)s0 * 256))[lane];
        ushort4 u1 = ((const ushort4*)(h + (size_t)s1 * 256))[lane];
        ushort4 u2 = ((const ushort4*)(h + (size_t)s2 * 256))[lane];
        ushort4 u3 = ((const ushort4*)(h + (size_t)s3 * 256))[lane];
        float e0 = pick4(as0, head) + ad_h; e0 = e0 > 0.f ? e0 : NEG_SLOPE * e0;
        float e1 = pick4(as1, head) + ad_h; e1 = e1 > 0.f ? e1 : NEG_SLOPE * e1;
        float e2 = pick4(as2, head) + ad_h; e2 = e2 > 0.f ? e2 : NEG_SLOPE * e2;
        float e3 = pick4(as3, head) + ad_h; e3 = e3 > 0.f ? e3 : NEG_SLOPE * e3;
        float p0 = __expf(e0), p1 = __expf(e1), p2 = __expf(e2), p3 = __expf(e3);
        den += p0 + p1 + p2 + p3;
        acc.x += p0 * bf2f(u0.x) + p1 * bf2f(u1.x) + p2 * bf2f(u2.x) + p3 * bf2f(u3.x);
        acc.y += p0 * bf2f(u0.y) + p1 * bf2f(u1.y) + p2 * bf2f(u2.y) + p3 * bf2f(u3.y);
        acc.z += p0 * bf2f(u0.z) + p1 * bf2f(u1.z) + p2 * bf2f(u2.z) + p3 * bf2f(u3.z);
        acc.w += p0 * bf2f(u0.w) + p1 * bf2f(u1.w) + p2 * bf2f(u2.w) + p3 * bf2f(u3.w);
    }
    for (; i < o1; ++i) {
        int s = __builtin_amdgcn_readfirstlane(csr_src[i]);
        float4 asv = *(const float4*)&als[s * 4];
        ushort4 uv = ((const ushort4*)(h + (size_t)s * 256))[lane];
        float e = pick4(asv, head) + ad_h;
        e = e > 0.f ? e : NEG_SLOPE * e;
        float p = __expf(e);
        den += p;
        acc.x += p * bf2f(uv.x); acc.y += p * bf2f(uv.y);
        acc.z += p * bf2f(uv.z); acc.w += p * bf2f(uv.w);
    }

    const float rden = 1.f / den;
    float c0 = acc.x * rden, c1 = acc.y * rden, c2 = acc.z * rden, c3 = acc.w * rden;
    c0 += __shfl_xor(c0, 16, 64); c0 += __shfl_xor(c0, 32, 64);
    c1 += __shfl_xor(c1, 16, 64); c1 += __shfl_xor(c1, 32, 64);
    c2 += __shfl_xor(c2, 16, 64); c2 += __shfl_xor(c2, 32, 64);
    c3 += __shfl_xor(c3, 16, 64); c3 += __shfl_xor(c3, 32, 64);

    if (lane < 16) {
        float4 bv = *(const float4*)&bias[d4];
        float v0 = 0.25f * c0 + bv.x;
        float v1 = 0.25f * c1 + bv.y;
        float v2 = 0.25f * c2 + bv.z;
        float v3 = 0.25f * c3 + bv.w;
        float4 o;
        o.x = v0 > 0.f ? v0 : 0.f;
        o.y = v1 > 0.f ? v1 : 0.f;
        o.z = v2 > 0.f ? v2 : 0.f;
        o.w = v3 > 0.f ? v3 : 0.f;
        *(float4*)&hout[(size_t)n * 64 + d4] = o;
    }
}

// ---------------- per-graph pooling ----------------
__global__ __launch_bounds__(256)
void pool_kernel(const float* __restrict__ hout, float* __restrict__ pooled, int layer) {
    const int wid = threadIdx.x >> 6, lane = threadIdx.x & 63;
    const int g = blockIdx.x * 4 + wid;
    float s = 0.f;
    const float* p = &hout[(size_t)g * NPG * 64 + lane];
    #pragma unroll 8
    for (int i = 0; i < NPG; ++i) s += p[i * 64];
    pooled[(g * NLAYERS + layer) * 64 + lane] = s;
}

// ---------------- final layer-attention ----------------
__global__ __launch_bounds__(256)
void final_kernel(const float* __restrict__ pooled, const float* __restrict__ pw,
                  const float* __restrict__ pb, float* __restrict__ out) {
    const int wid = threadIdx.x >> 6, lane = threadIdx.x & 63;
    const int g = blockIdx.x * 4 + wid;
    float v0 = pooled[(g * 3 + 0) * 64 + lane];
    float v1 = pooled[(g * 3 + 1) * 64 + lane];
    float v2 = pooled[(g * 3 + 2) * 64 + lane];
    float w = pw[lane];
    float l0 = v0 * w, l1 = v1 * w, l2 = v2 * w;
    #pragma unroll
    for (int m = 1; m < 64; m <<= 1) {
        l0 += __shfl_xor(l0, m, 64);
        l1 += __shfl_xor(l1, m, 64);
        l2 += __shfl_xor(l2, m, 64);
    }
    float bb = pb[0];
    l0 += bb; l1 += bb; l2 += bb;
    float mx = fmaxf(l0, fmaxf(l1, l2));
    float e0 = __expf(l0 - mx), e1 = __expf(l1 - mx), e2 = __expf(l2 - mx);
    float inv = 1.f / (e0 + e1 + e2);
    out[(size_t)g * 64 + lane] = (v0 * e0 + v1 * e1 + v2 * e2) * inv;
}

// ---------------- launch ----------------
extern "C" void kernel_launch(void* const* d_in, const int* in_sizes, int n_in,
                              void* d_out, int out_size, void* d_ws, size_t ws_size,
                              hipStream_t stream) {
    const float* x  = (const float*)d_in[0];
    const int*   ei = (const int*)d_in[1];
    const float* W[3]    = {(const float*)d_in[3], (const float*)d_in[7],  (const float*)d_in[11]};
    const float* asrc[3] = {(const float*)d_in[4], (const float*)d_in[8],  (const float*)d_in[12]};
    const float* adst[3] = {(const float*)d_in[5], (const float*)d_in[9],  (const float*)d_in[13]};
    const float* bias[3] = {(const float*)d_in[6], (const float*)d_in[10], (const float*)d_in[14]};
    const float* pw = (const float*)d_in[15];
    const float* pb = (const float*)d_in[16];
    float* out = (float*)d_out;

    char* ws = (char*)d_ws;
    size_t off = 0;
    auto alloc = [&](size_t bytes) -> void* {
        void* p = ws + off;
        off = (off + bytes + 255) & ~(size_t)255;
        return p;
    };
    int*   offsets = (int*)alloc((N_NODES + 1) * 4);
    int*   cursor  = (int*)alloc(N_NODES * 4);
    int*   csr_src = (int*)alloc((size_t)(N_EDGES + N_NODES) * 4);
    unsigned short* h = (unsigned short*)alloc((size_t)N_NODES * 256 * 2);  // 67 MB bf16
    float* als     = (float*)alloc((size_t)N_NODES * 4 * 4);
    float* ald     = (float*)alloc((size_t)N_NODES * 4 * 4);
    float* hbuf0   = (float*)alloc((size_t)N_NODES * 64 * 4);
    float* hbuf1   = (float*)alloc((size_t)N_NODES * 64 * 4);
    float* pooled  = (float*)alloc((size_t)NG * 3 * 64 * 4);
    unsigned short* WtH = (unsigned short*)alloc((size_t)256 * 96 * 2);
    unsigned short* WtL = (unsigned short*)alloc((size_t)256 * 96 * 2);
    (void)ws_size; (void)in_sizes; (void)n_in; (void)out_size;

    const int* srcp = ei;
    const int* dstp = ei + N_EDGES;

    init_counts<<<N_NODES / 256, 256, 0, stream>>>(cursor);
    count_edges<<<N_EDGES / 256, 256, 0, stream>>>(dstp, cursor);
    scan_kernel<<<1, 1024, 0, stream>>>(cursor, offsets);
    place_self<<<N_NODES / 256, 256, 0, stream>>>(offsets, cursor, csr_src);
    scatter_edges<<<N_EDGES / 256, 256, 0, stream>>>(srcp, dstp, cursor, csr_src);

    const float* in = x;
    for (int l = 0; l < 3; ++l) {
        const int K = (l == 0) ? IN_DIM_ : HID_;
        wsplit<<<96, 256, 0, stream>>>(W[l], K, WtH, WtL);
        if (l == 0)
            gemm_mfma<3, IN_DIM_><<<N_NODES / 64, 256, 0, stream>>>(in, WtH, WtL, asrc[l], adst[l], h, als, ald);
        else
            gemm_mfma<2, HID_><<<N_NODES / 64, 256, 0, stream>>>(in, WtH, WtL, asrc[l], adst[l], h, als, ald);
        float* ho = (l & 1) ? hbuf1 : hbuf0;
        aggregate<<<N_NODES / 4, 256, 0, stream>>>(offsets, csr_src, h, als, ald, bias[l], ho);
        pool_kernel<<<NG / 4, 256, 0, stream>>>(ho, pooled, l);
        in = ho;
    }
    final_kernel<<<NG / 4, 256, 0, stream>>>(pooled, pw, pb, out);
}